// Round 16
// baseline (2094.775 us; speedup 1.0000x reference)
//
#include <hip/hip_runtime.h>
#include <hip/hip_bf16.h>

typedef __hip_bfloat16 bf16;
typedef __attribute__((ext_vector_type(8))) short bf16x8;
typedef __attribute__((ext_vector_type(4))) float f32x4;

static constexpr int Bb = 512;
static constexpr int Hh = 512;
static constexpr int Ll = 64;
static constexpr int Vv = 1024;
static constexpr int MAXNB = 8;
static constexpr int Tt = 46;          // 2*(N-1)
static constexpr int TB = Tt * Bb;     // 23552, also PAD index
static constexpr int PADID = TB;
static constexpr int NROWS = TB + Bb;  // 24064
static constexpr int XPS = 3 * Hh;     // xproj row stride (bf16 elems)

// MFMA head geometry (BM=16 tiles)
static constexpr int KU  = 2 * Hh + Ll;  // 1088 (stop K)
static constexpr int KUP = KU + 8;       // 1096 padded
static constexpr int KW  = Hh + Ll;      // 576 (pred L1 K)
static constexpr int KWP = KW + 8;       // 584 padded
static constexpr int HP  = Hh + 8;       // 520 padded hid stride

// tiled-weight col-tile counts (N/16)
static constexpr int NT_U  = Hh / 16;    // 32 (N=512 weights)
static constexpr int NT_WO = Vv / 16;    // 64 (wtWo: N=1024)

__device__ __forceinline__ float b2f(bf16 v) { return __bfloat162float(v); }
__device__ __forceinline__ float sigm(float x) { return 1.f / (1.f + __expf(-x)); }
__device__ __forceinline__ float bfu(unsigned short u) {
  return __uint_as_float((unsigned)u << 16);
}
__device__ __forceinline__ unsigned short f2bfu(float x) {
  bf16 v = __float2bfloat16(x);
  return *(unsigned short*)&v;
}

// dtype-adaptive load: F32 ? fp32 tensor : bf16 tensor
template <bool F32>
__device__ __forceinline__ float ldv(const void* p, long i) {
  if (F32) return ((const float*)p)[i];
  return __bfloat162float(((const bf16*)p)[i]);
}

// ---------------------------------------------------------------------------
// dtype probe
// ---------------------------------------------------------------------------
__global__ void detect_kernel(const unsigned short* __restrict__ embu,
                              int* __restrict__ flag) {
  const long n = (long)Vv * Hh;
  int bad = 0;
  for (long i = blockIdx.x * 256 + threadIdx.x; i < n; i += 256L * 64) {
    unsigned short u = embu[i];
    if ((u & 0x7F80u) == 0x7F80u) bad = 1;
  }
  if (bad) atomicOr(flag, 1);
}

// ---------------------------------------------------------------------------
// xproj[v] = [emb[v]@Wz[:H]+bz | emb[v]@Wr+br | emb[v]@Wh[:H]+bh], bf16 out.
// ---------------------------------------------------------------------------
template <bool F32>
__device__ void xproj_body(const void* emb, const void* Wz, const void* bz,
                           const void* Wr, const void* br, const void* Wh,
                           const void* bh, bf16* xproj, float* xe) {
  const int v = blockIdx.x, k = threadIdx.x;
  xe[k] = ldv<F32>(emb, (long)v * Hh + k);
  __syncthreads();
  float z = ldv<F32>(bz, k);
  float r = ldv<F32>(br, k);
  float h = ldv<F32>(bh, k);
  for (int i = 0; i < Hh; ++i) {
    float a = xe[i];
    z += a * ldv<F32>(Wz, (long)i * Hh + k);
    r += a * ldv<F32>(Wr, (long)i * Hh + k);
    h += a * ldv<F32>(Wh, (long)i * Hh + k);
  }
  bf16* xp = xproj + (long)v * XPS;
  xp[k]          = __float2bfloat16(z);
  xp[Hh + k]     = __float2bfloat16(r);
  xp[2 * Hh + k] = __float2bfloat16(h);
}

__global__ __launch_bounds__(512) void xproj_kernel(
    const void* emb, const void* Wz, const void* bz, const void* Wr,
    const void* br, const void* Wh, const void* bh, bf16* xproj,
    const int* __restrict__ flag) {
  __shared__ float xe[Hh];
  if (*flag)
    xproj_body<true>(emb, Wz, bz, Wr, br, Wh, bh, xproj, xe);
  else
    xproj_body<false>(emb, Wz, bz, Wr, br, Wh, bh, xproj, xe);
}

// ---------------------------------------------------------------------------
// Tiled weight transposes, fragment-native layout (R11-proven):
// element (n, k) -> ((k>>5)*NT + (n>>4))*512 + ((k&31)>>3)*128 + (n&15)*8
//                   + (k&7). One wave B-frag = consecutive 1KB.
// ro = source row offset (for Wz/Wh lower halves).
// ---------------------------------------------------------------------------
template <bool F32>
__device__ __forceinline__ void wtt_body(const void* src, bf16* dst, int K,
                                         int N, int NT, int ro, int tk0,
                                         int tn0, unsigned short (*tile)[65]) {
  const int tid = threadIdx.x;
  const int ln = tid & 63;
  const int gr = tid >> 6;  // 0..3
  for (int kk = gr; kk < 64; kk += 4) {
    const int k = tk0 + kk, n = tn0 + ln;
    tile[ln][kk] = f2bfu(ldv<F32>(src, (long)(ro + k) * N + n));
  }
  __syncthreads();
  for (int nn = gr; nn < 64; nn += 4) {
    const int n = tn0 + nn, k = tk0 + ln;
    const long off = ((long)(k >> 5) * NT + (n >> 4)) * 512 +
                     ((k & 31) >> 3) * 128 + (n & 15) * 8 + (k & 7);
    dst[off] = *(bf16*)&tile[nn][ln];
  }
}

__global__ __launch_bounds__(256) void wt_kernel(
    const void* W, const void* U, const void* Wo, const void* Wz,
    const void* Ur, const void* Wh, bf16* wtW, bf16* wtU, bf16* wtWo,
    bf16* wgZ, bf16* wgR, bf16* wgH2, const int* __restrict__ flag) {
  __shared__ unsigned short tile[64][65];
  int b = blockIdx.x;
  const void* src; bf16* dst; int K, N, NT, ro, tk, tn;
  if (b < 72) {            // W: K=576, N=512 -> 9x8 tiles
    src = W; dst = wtW; K = KW; N = Hh; NT = NT_U; ro = 0; tk = b / 8; tn = b % 8;
  } else if (b < 208) {    // U: K=1088, N=512 -> 17x8 tiles
    b -= 72; src = U; dst = wtU; K = KU; N = Hh; NT = NT_U; ro = 0; tk = b / 8; tn = b % 8;
  } else if (b < 336) {    // Wo: K=512, N=1024 -> 8x16 tiles
    b -= 208; src = Wo; dst = wtWo; K = Hh; N = Vv; NT = NT_WO; ro = 0; tk = b / 16; tn = b % 16;
  } else if (b < 400) {    // Wz lower half (rows Hh..2Hh): 8x8 tiles
    b -= 336; src = Wz; dst = wgZ; K = Hh; N = Hh; NT = NT_U; ro = Hh; tk = b / 8; tn = b % 8;
  } else if (b < 464) {    // Ur: 8x8 tiles
    b -= 400; src = Ur; dst = wgR; K = Hh; N = Hh; NT = NT_U; ro = 0; tk = b / 8; tn = b % 8;
  } else {                 // Wh lower half: 8x8 tiles
    b -= 464; src = Wh; dst = wgH2; K = Hh; N = Hh; NT = NT_U; ro = Hh; tk = b / 8; tn = b % 8;
  }
  if (*flag) wtt_body<true>(src, dst, K, N, NT, ro, tk * 64, tn * 64, tile);
  else       wtt_body<false>(src, dst, K, N, NT, ro, tk * 64, tn * 64, tile);
}

// ---------------------------------------------------------------------------
// Shared neighbor-prep (2-mol variants; fallback kernels).
// ---------------------------------------------------------------------------
__device__ __forceinline__ int gru_prep(int t, int b0, const int* hni,
                                        int* cid, int* rowf, int* nvs) {
  const int k = threadIdx.x;
  if (k < 2 * MAXNB)
    cid[k] = hni[((long)t * Bb + b0 + (k >> 3)) * MAXNB + (k & 7)];
  __syncthreads();
  if (k == 0) {
    int n0 = 0; while (n0 < MAXNB && cid[n0] != PADID) ++n0;
    int n1 = 0; while (n1 < MAXNB && cid[MAXNB + n1] != PADID) ++n1;
    for (int j = 0; j < n1; ++j) cid[n0 + j] = cid[MAXNB + j];
    for (int p = 0; p < n0 + n1; ++p) rowf[p] = (p >= n0) ? 1 : 0;
    nvs[0] = n0; nvs[1] = n1;
  }
  __syncthreads();
  return nvs[0] + nvs[1];
}

// 4-mol prep: stages 32 raw ids into cid[32..63], compacts to cid[0..P) with
// rowf[p] = mol index 0..3. Source lists are front-packed (PAD-terminated).
__device__ __forceinline__ int gru_prep4(int t, int b0, const int* hni,
                                         int* cid, int* rowf, int* nvs) {
  const int k = threadIdx.x;
  if (k < 4 * MAXNB)
    cid[32 + k] = hni[((long)t * Bb + b0 + (k >> 3)) * MAXNB + (k & 7)];
  __syncthreads();
  if (k == 0) {
    int P = 0;
    for (int m = 0; m < 4; ++m)
      for (int j = 0; j < MAXNB; ++j) {
        const int v = cid[32 + m * MAXNB + j];
        if (v == PADID) break;
        cid[P] = v; rowf[P] = m; ++P;
      }
    nvs[0] = P;
  }
  __syncthreads();
  return nvs[0];
}

// ---------------------------------------------------------------------------
// MFMA GEMV phase for the GRU step: out[s][col] = sum_i A[s][i]*Wt[col][i],
// S <= 4 streams, 512 cols, K=512. 8 waves x 64 cols; A rows beyond S are
// zero; B frags are 1KB coalesced (tiled layout). Writes red[s*Hh + col].
//   ABF ? A is bf16 LDS (stride Hh) : A is f32 LDS (stride Hh)
// ---------------------------------------------------------------------------
template <bool ABF, int S>
__device__ __forceinline__ void mfma_gemv(const bf16* __restrict__ Wt,
                                          const void* __restrict__ Abase,
                                          float* __restrict__ red,
                                          int wv, int l) {
  const int arow = l & 15;
  const int kofs = (l >> 4) * 8;
  f32x4 acc[4];
#pragma unroll
  for (int f = 0; f < 4; ++f) acc[f] = (f32x4){0.f, 0.f, 0.f, 0.f};

  for (int k0 = 0; k0 < Hh; k0 += 32) {
    unsigned short av[8] = {0, 0, 0, 0, 0, 0, 0, 0};
    if (arow < S) {
      if (ABF) {
        *(int4*)av = *(const int4*)((const bf16*)Abase + (long)arow * Hh +
                                    k0 + kofs);
      } else {
        const float* s = (const float*)Abase + (long)arow * Hh + k0 + kofs;
#pragma unroll
        for (int e = 0; e < 8; ++e) av[e] = f2bfu(s[e]);
      }
    }
    const bf16x8 a = *(const bf16x8*)av;
    const bf16* bkb = Wt + ((long)(k0 >> 5) * NT_U + wv * 4) * 512 + l * 8;
#pragma unroll
    for (int f = 0; f < 4; ++f) {
      const bf16x8 b = *(const bf16x8*)(bkb + f * 512);
      acc[f] = __builtin_amdgcn_mfma_f32_16x16x32_bf16(a, b, acc[f], 0, 0, 0);
    }
  }
#pragma unroll
  for (int f = 0; f < 4; ++f) {
    const int col = wv * 64 + f * 16 + (l & 15);
#pragma unroll
    for (int r = 0; r < 4; ++r) {
      const int row = (l >> 4) * 4 + r;
      if (row < S) red[row * Hh + col] = acc[f][r];
    }
  }
}

// ---------------------------------------------------------------------------
// GRU scan step, MFMA variant, 4 mols per block (grid 128, 512 threads).
// z/h phases stream wgZ/wgH2 ONCE for 4 mols (same MFMA count as 2-mol:
// rows 0..3 of the 16-row A fragment all productive). sum_g chunks of 4
// pairs via wgR as proven. LDS ~56 KB -> 1 block/CU at grid 128; only 16
// CUs/XCD active -> each gets ~2x the per-XCD L2 BW share.
// ---------------------------------------------------------------------------
__global__ __launch_bounds__(512) void gru_step_xpb(
    int t, const int* __restrict__ wid, const int* __restrict__ hni,
    const bf16* __restrict__ xproj, const bf16* __restrict__ wgZ,
    const bf16* __restrict__ wgR, const bf16* __restrict__ wgH2,
    bf16* __restrict__ hbuf) {
  __shared__ float sh[4 * Hh];                                  // 8 KB
  __shared__ float sg[4 * Hh];                                  // 8 KB
  __shared__ __align__(16) unsigned short hnc[4 * MAXNB * Hh];  // 32 KB
  __shared__ float red[4 * Hh];                                 // 8 KB
  __shared__ int   cid[64];
  __shared__ int   rowf[4 * MAXNB];
  __shared__ int   nvs[2];

  const int tid = threadIdx.x;
  const int k = tid;
  const int wv_ = tid >> 6;
  const int l = tid & 63;
  const int b0 = blockIdx.x * 4;
  const int P = gru_prep4(t, b0, hni, cid, rowf, nvs);

  const bf16* xp0 = xproj + (long)wid[t * Bb + b0] * XPS;
  const bf16* xp1 = xproj + (long)wid[t * Bb + b0 + 1] * XPS;
  const bf16* xp2 = xproj + (long)wid[t * Bb + b0 + 2] * XPS;
  const bf16* xp3 = xproj + (long)wid[t * Bb + b0 + 3] * XPS;

  // gather neighbor h rows into LDS (bf16, lossless), one wave per row
  for (int p = wv_; p < P; p += 8) {
    const int4 d = *(const int4*)(hbuf + (long)cid[p] * Hh + 8 * l);
    *(int4*)(hnc + p * Hh + 8 * l) = d;
  }
  __syncthreads();

  float s0 = 0.f, s1 = 0.f, s2 = 0.f, s3 = 0.f;
  for (int p = 0; p < P; ++p) {
    const float hv = bfu(hnc[p * Hh + k]);
    const int m = rowf[p];
    if (m == 0) s0 += hv; else if (m == 1) s1 += hv;
    else if (m == 2) s2 += hv; else s3 += hv;
  }
  sh[k] = s0; sh[Hh + k] = s1; sh[2 * Hh + k] = s2; sh[3 * Hh + k] = s3;
  const float xz0 = b2f(xp0[k]),          xz1 = b2f(xp1[k]);
  const float xz2 = b2f(xp2[k]),          xz3 = b2f(xp3[k]);
  const float xr0 = b2f(xp0[Hh + k]),     xr1 = b2f(xp1[Hh + k]);
  const float xr2 = b2f(xp2[Hh + k]),     xr3 = b2f(xp3[Hh + k]);
  const float xh0 = b2f(xp0[2 * Hh + k]), xh1 = b2f(xp1[2 * Hh + k]);
  const float xh2 = b2f(xp2[2 * Hh + k]), xh3 = b2f(xp3[2 * Hh + k]);
  __syncthreads();

  // ---- z pre-activation: xz + sum_h @ WzH (one MFMA pass, 4 mols) ----
  mfma_gemv<false, 4>(wgZ, sh, red, wv_, l);
  __syncthreads();
  const float zp0 = xz0 + red[k];
  const float zp1 = xz1 + red[Hh + k];
  const float zp2 = xz2 + red[2 * Hh + k];
  const float zp3 = xz3 + red[3 * Hh + k];
  __syncthreads();  // red reused below

  // ---- sum_g: chunks of up to 4 pairs through Ur (MFMA) ----
  float g0 = 0.f, g1 = 0.f, g2 = 0.f, g3 = 0.f;
  for (int c = 0; c < P; c += 4) {
    const int ns = (P - c >= 4) ? 4 : (P - c);
    const unsigned short* Ab = hnc + c * Hh;
    switch (ns) {
      case 1: mfma_gemv<true, 1>(wgR, Ab, red, wv_, l); break;
      case 2: mfma_gemv<true, 2>(wgR, Ab, red, wv_, l); break;
      case 3: mfma_gemv<true, 3>(wgR, Ab, red, wv_, l); break;
      default: mfma_gemv<true, 4>(wgR, Ab, red, wv_, l); break;
    }
    __syncthreads();
    for (int q = 0; q < ns; ++q) {
      const int p = c + q;
      const int m = rowf[p];
      const float xrm = (m == 0) ? xr0 : (m == 1) ? xr1 : (m == 2) ? xr2 : xr3;
      const float cc = sigm(xrm + red[q * Hh + k]) * bfu(hnc[p * Hh + k]);
      if (m == 0) g0 += cc; else if (m == 1) g1 += cc;
      else if (m == 2) g2 += cc; else g3 += cc;
    }
    __syncthreads();  // red reused next chunk / by h phase
  }
  sg[k] = g0; sg[Hh + k] = g1; sg[2 * Hh + k] = g2; sg[3 * Hh + k] = g3;
  __syncthreads();

  // ---- h_tilde pre-activation: xh + sum_g @ WhH (one MFMA pass, 4 mols) ----
  mfma_gemv<false, 4>(wgH2, sg, red, wv_, l);
  __syncthreads();
  const float hp0 = xh0 + red[k];
  const float hp1 = xh1 + red[Hh + k];
  const float hp2 = xh2 + red[2 * Hh + k];
  const float hp3 = xh3 + red[3 * Hh + k];

  float z;
  z = sigm(zp0); const float o0 = (1.f - z) * s0 + z * tanhf(hp0);
  z = sigm(zp1); const float o1 = (1.f - z) * s1 + z * tanhf(hp1);
  z = sigm(zp2); const float o2 = (1.f - z) * s2 + z * tanhf(hp2);
  z = sigm(zp3); const float o3 = (1.f - z) * s3 + z * tanhf(hp3);
  hbuf[((long)t * Bb + b0) * Hh + k]     = __float2bfloat16(o0);
  hbuf[((long)t * Bb + b0 + 1) * Hh + k] = __float2bfloat16(o1);
  hbuf[((long)t * Bb + b0 + 2) * Hh + k] = __float2bfloat16(o2);
  hbuf[((long)t * Bb + b0 + 3) * Hh + k] = __float2bfloat16(o3);
}

// ---------------------------------------------------------------------------
// R1 K-split GEMV phase (proven fallback — do not touch).
// ---------------------------------------------------------------------------
template <bool F32, bool ABF, int S>
__device__ __forceinline__ void gemv_phase(const void* __restrict__ Wp,
                                           long wrow0,
                                           const void* __restrict__ Abase,
                                           float* __restrict__ red,
                                           int kg, int ch0) {
  float acc[S][4];
#pragma unroll
  for (int s = 0; s < S; ++s)
#pragma unroll
    for (int j = 0; j < 4; ++j) acc[s][j] = 0.f;
  const int i0 = kg * 128;
#pragma unroll 4
  for (int ii = 0; ii < 128; ++ii) {
    const int i = i0 + ii;
    float wv[4];
    if (F32) {
      const float4 f =
          *(const float4*)((const float*)Wp + (wrow0 + i) * (long)Hh + ch0);
      wv[0] = f.x; wv[1] = f.y; wv[2] = f.z; wv[3] = f.w;
    } else {
      const uint2 d =
          *(const uint2*)((const bf16*)Wp + (wrow0 + i) * (long)Hh + ch0);
      wv[0] = __uint_as_float(d.x << 16);
      wv[1] = __uint_as_float(d.x & 0xffff0000u);
      wv[2] = __uint_as_float(d.y << 16);
      wv[3] = __uint_as_float(d.y & 0xffff0000u);
    }
#pragma unroll
    for (int s = 0; s < S; ++s) {
      const float a = ABF
          ? __bfloat162float(((const bf16*)Abase)[s * Hh + i])
          : ((const float*)Abase)[s * Hh + i];
#pragma unroll
      for (int j = 0; j < 4; ++j) acc[s][j] += a * wv[j];
    }
  }
#pragma unroll
  for (int s = 0; s < S; ++s)
#pragma unroll
    for (int j = 0; j < 4; ++j)
      red[(kg * 4 + s) * Hh + ch0 + j] = acc[s][j];
}

// ---------------------------------------------------------------------------
// GRU scan step, xproj variant — R1 proven fallback (original weights).
// ---------------------------------------------------------------------------
template <bool F32>
__device__ void gru_body_xp(int t, const int* wid, const int* hni,
                            const bf16* xproj, const void* Wz, const void* Ur,
                            const void* Wh, bf16* hbuf, float* sh, float* sg,
                            unsigned short* hnc, float* red, int* cid,
                            int* rowf, int* nvs) {
  const int tid = threadIdx.x;
  const int k = tid;
  const int wv_ = tid >> 6;
  const int l = tid & 63;
  const int kg = wv_ >> 1;
  const int ch0 = (wv_ & 1) * 256 + l * 4;
  const int b0 = blockIdx.x * 2;
  const int P = gru_prep(t, b0, hni, cid, rowf, nvs);

  const int w0 = wid[t * Bb + b0];
  const int w1 = wid[t * Bb + b0 + 1];
  const bf16* xp0 = xproj + (long)w0 * XPS;
  const bf16* xp1 = xproj + (long)w1 * XPS;

  for (int p = wv_; p < P; p += 8) {
    const int4 d = *(const int4*)(hbuf + (long)cid[p] * Hh + 8 * l);
    *(int4*)(hnc + p * Hh + 8 * l) = d;
  }
  __syncthreads();

  float s0 = 0.f, s1 = 0.f;
  for (int p = 0; p < P; ++p) {
    const float hv = __bfloat162float(((const bf16*)hnc)[p * Hh + k]);
    if (rowf[p]) s1 += hv; else s0 += hv;
  }
  sh[k] = s0; sh[Hh + k] = s1;
  const float xz0 = b2f(xp0[k]),          xz1 = b2f(xp1[k]);
  const float xr0 = b2f(xp0[Hh + k]),     xr1 = b2f(xp1[Hh + k]);
  const float xh0 = b2f(xp0[2 * Hh + k]), xh1 = b2f(xp1[2 * Hh + k]);
  __syncthreads();

  gemv_phase<F32, false, 2>(Wz, Hh, sh, red, kg, ch0);
  __syncthreads();
  float zp0 = xz0, zp1 = xz1;
#pragma unroll
  for (int g = 0; g < 4; ++g) {
    zp0 += red[(g * 4 + 0) * Hh + k];
    zp1 += red[(g * 4 + 1) * Hh + k];
  }
  __syncthreads();

  float g0 = 0.f, g1 = 0.f;
  for (int c = 0; c < P; c += 4) {
    const int ns = (P - c >= 4) ? 4 : (P - c);
    const unsigned short* Ab = hnc + c * Hh;
    switch (ns) {
      case 1: gemv_phase<F32, true, 1>(Ur, 0, Ab, red, kg, ch0); break;
      case 2: gemv_phase<F32, true, 2>(Ur, 0, Ab, red, kg, ch0); break;
      case 3: gemv_phase<F32, true, 3>(Ur, 0, Ab, red, kg, ch0); break;
      default: gemv_phase<F32, true, 4>(Ur, 0, Ab, red, kg, ch0); break;
    }
    __syncthreads();
    for (int q = 0; q < ns; ++q) {
      const int p = c + q;
      float rp = rowf[p] ? xr1 : xr0;
#pragma unroll
      for (int g = 0; g < 4; ++g) rp += red[(g * 4 + q) * Hh + k];
      const float cc =
          sigm(rp) * __bfloat162float(((const bf16*)hnc)[p * Hh + k]);
      if (rowf[p]) g1 += cc; else g0 += cc;
    }
    __syncthreads();
  }
  sg[k] = g0; sg[Hh + k] = g1;
  __syncthreads();

  gemv_phase<F32, false, 2>(Wh, Hh, sg, red, kg, ch0);
  __syncthreads();
  float hp0 = xh0, hp1 = xh1;
#pragma unroll
  for (int g = 0; g < 4; ++g) {
    hp0 += red[(g * 4 + 0) * Hh + k];
    hp1 += red[(g * 4 + 1) * Hh + k];
  }

  float z;
  z = sigm(zp0); const float o0 = (1.f - z) * s0 + z * tanhf(hp0);
  z = sigm(zp1); const float o1 = (1.f - z) * s1 + z * tanhf(hp1);
  hbuf[((long)t * Bb + b0) * Hh + k]     = __float2bfloat16(o0);
  hbuf[((long)t * Bb + b0 + 1) * Hh + k] = __float2bfloat16(o1);
}

__global__ __launch_bounds__(512) void gru_step_xp(
    int t, const int* __restrict__ wid, const int* __restrict__ hni,
    const bf16* xproj, const void* Wz, const void* Ur, const void* Wh,
    bf16* hbuf, const int* __restrict__ flag) {
  __shared__ float sh[2 * Hh];
  __shared__ float sg[2 * Hh];
  __shared__ __align__(16) unsigned short hnc[2 * MAXNB * Hh];
  __shared__ float red[4 * 4 * Hh];
  __shared__ int   cid[2 * MAXNB];
  __shared__ int   rowf[2 * MAXNB];
  __shared__ int   nvs[2];
  if (*flag)
    gru_body_xp<true>(t, wid, hni, xproj, Wz, Ur, Wh, hbuf, sh, sg, hnc, red,
                      cid, rowf, nvs);
  else
    gru_body_xp<false>(t, wid, hni, xproj, Wz, Ur, Wh, hbuf, sh, sg, hnc, red,
                       cid, rowf, nvs);
}

// ---------------------------------------------------------------------------
// Legacy fallback (no xproj buffer).
// ---------------------------------------------------------------------------
template <bool F32, int P>
__device__ __forceinline__ void sumg(const void* Ur, int k, const float* hnc,
                                     float p0, float p1, const int* rowf,
                                     float& g0, float& g1) {
  float a[P];
#pragma unroll
  for (int p = 0; p < P; ++p) a[p] = rowf[p] ? p1 : p0;
  for (int i = 0; i < Hh; ++i) {
    float uv = ldv<F32>(Ur, (long)i * Hh + k);
#pragma unroll
    for (int p = 0; p < P; ++p) a[p] += hnc[p * Hh + i] * uv;
  }
#pragma unroll
  for (int p = 0; p < P; ++p) {
    float c = sigm(a[p]) * hnc[p * Hh + k];
    if (rowf[p]) g1 += c; else g0 += c;
  }
}

#define SUMG_SWITCH(F32V)                                                     \
  switch (P) {                                                                \
    case 1:  sumg<F32V, 1 >(Ur, k, hnc, p0, p1, rowf, g0, g1); break;         \
    case 2:  sumg<F32V, 2 >(Ur, k, hnc, p0, p1, rowf, g0, g1); break;         \
    case 3:  sumg<F32V, 3 >(Ur, k, hnc, p0, p1, rowf, g0, g1); break;         \
    case 4:  sumg<F32V, 4 >(Ur, k, hnc, p0, p1, rowf, g0, g1); break;         \
    case 5:  sumg<F32V, 5 >(Ur, k, hnc, p0, p1, rowf, g0, g1); break;         \
    case 6:  sumg<F32V, 6 >(Ur, k, hnc, p0, p1, rowf, g0, g1); break;         \
    case 7:  sumg<F32V, 7 >(Ur, k, hnc, p0, p1, rowf, g0, g1); break;         \
    case 8:  sumg<F32V, 8 >(Ur, k, hnc, p0, p1, rowf, g0, g1); break;         \
    case 9:  sumg<F32V, 9 >(Ur, k, hnc, p0, p1, rowf, g0, g1); break;         \
    case 10: sumg<F32V, 10>(Ur, k, hnc, p0, p1, rowf, g0, g1); break;         \
    case 11: sumg<F32V, 11>(Ur, k, hnc, p0, p1, rowf, g0, g1); break;         \
    case 12: sumg<F32V, 12>(Ur, k, hnc, p0, p1, rowf, g0, g1); break;         \
    case 13: sumg<F32V, 13>(Ur, k, hnc, p0, p1, rowf, g0, g1); break;         \
    case 14: sumg<F32V, 14>(Ur, k, hnc, p0, p1, rowf, g0, g1); break;         \
    case 15: sumg<F32V, 15>(Ur, k, hnc, p0, p1, rowf, g0, g1); break;         \
    case 16: sumg<F32V, 16>(Ur, k, hnc, p0, p1, rowf, g0, g1); break;         \
    default: break;                                                           \
  }

template <bool F32>
__device__ void gru_body(int t, const int* wid, const int* hni,
                         const void* emb, const void* Wz, const void* bz,
                         const void* Wr, const void* br, const void* Ur,
                         const void* Wh, const void* bh, bf16* hbuf,
                         float* xs, float* sh, float* sg, float* hnc,
                         int* cid, int* rowf, int* nvs) {
  const int k = threadIdx.x;
  const int b0 = blockIdx.x * 2;
  const int P = gru_prep(t, b0, hni, cid, rowf, nvs);

  const int w0 = wid[t * Bb + b0];
  const int w1 = wid[t * Bb + b0 + 1];
  xs[k]      = ldv<F32>(emb, (long)w0 * Hh + k);
  xs[Hh + k] = ldv<F32>(emb, (long)w1 * Hh + k);

  float s0 = 0.f, s1 = 0.f;
  for (int p = 0; p < P; ++p) {
    float hv = b2f(hbuf[(long)cid[p] * Hh + k]);
    hnc[p * Hh + k] = hv;
    if (rowf[p]) s1 += hv; else s0 += hv;
  }
  sh[k] = s0; sh[Hh + k] = s1;
  __syncthreads();

  float bzk = ldv<F32>(bz, k);
  float z0 = bzk, z1 = bzk;
  for (int i = 0; i < Hh; ++i) {
    float wv = ldv<F32>(Wz, (long)i * Hh + k);
    z0 += xs[i] * wv; z1 += xs[Hh + i] * wv;
  }
  for (int i = 0; i < Hh; ++i) {
    float wv = ldv<F32>(Wz, (long)(Hh + i) * Hh + k);
    z0 += sh[i] * wv; z1 += sh[Hh + i] * wv;
  }

  float brk = ldv<F32>(br, k);
  float p0 = brk, p1 = brk;
  for (int i = 0; i < Hh; ++i) {
    float wv = ldv<F32>(Wr, (long)i * Hh + k);
    p0 += xs[i] * wv; p1 += xs[Hh + i] * wv;
  }

  float g0 = 0.f, g1 = 0.f;
  SUMG_SWITCH(F32)
  sg[k] = g0; sg[Hh + k] = g1;
  __syncthreads();

  float bhk = ldv<F32>(bh, k);
  float h0 = bhk, h1 = bhk;
  for (int i = 0; i < Hh; ++i) {
    float wv = ldv<F32>(Wh, (long)i * Hh + k);
    h0 += xs[i] * wv; h1 += xs[Hh + i] * wv;
  }
  for (int i = 0; i < Hh; ++i) {
    float wv = ldv<F32>(Wh, (long)(Hh + i) * Hh + k);
    h0 += sg[i] * wv; h1 += sg[Hh + i] * wv;
  }

  float z;
  z = sigm(z0); float o0 = (1.f - z) * s0 + z * tanhf(h0);
  z = sigm(z1); float o1 = (1.f - z) * s1 + z * tanhf(h1);
  hbuf[((long)t * Bb + b0) * Hh + k]     = __float2bfloat16(o0);
  hbuf[((long)t * Bb + b0 + 1) * Hh + k] = __float2bfloat16(o1);
}

__global__ __launch_bounds__(512) void gru_step(
    int t, const int* __restrict__ wid, const int* __restrict__ hni,
    const void* emb, const void* Wz, const void* bz, const void* Wr,
    const void* br, const void* Ur, const void* Wh, const void* bh,
    bf16* hbuf, const int* __restrict__ flag) {
  __shared__ float xs[2 * Hh];
  __shared__ float sh[2 * Hh];
  __shared__ float sg[2 * Hh];
  __shared__ float hnc[2 * MAXNB * Hh];
  __shared__ int   cid[2 * MAXNB];
  __shared__ int   rowf[2 * MAXNB];
  __shared__ int   nvs[2];
  if (*flag)
    gru_body<true>(t, wid, hni, emb, Wz, bz, Wr, br, Ur, Wh, bh, hbuf,
                   xs, sh, sg, hnc, cid, rowf, nvs);
  else
    gru_body<false>(t, wid, hni, emb, Wz, bz, Wr, br, Ur, Wh, bh, hbuf,
                    xs, sh, sg, hnc, cid, rowf, nvs);
}

// ===========================================================================
// MFMA stop head, BM=16 / 256 threads / grid NROWS/16, tiled-B loads.
// (R11-proven, unchanged.)
// ===========================================================================
template <bool F32>
__device__ void stop_mfma_body(
    const void* mol_vec, const int* wid, const int* dirs, const int* oni,
    const int* root_wid, const int* roni, const void* emb,
    const bf16* __restrict__ wtU, const void* bU, const void* Us,
    const void* bs, const bf16* __restrict__ hbuf, float* accum,
    unsigned short* As, float* bU_l, float* Us_l, int* wl, int* bl,
    float* tgl, int* idsl, float* sred) {
  const int tid = threadIdx.x;
  const int l = tid & 63, w = tid >> 6;  // w: 0..3
  const int r0 = blockIdx.x * 16;

  bU_l[tid] = ldv<F32>(bU, tid);
  bU_l[tid + 256] = ldv<F32>(bU, tid + 256);
  Us_l[tid] = ldv<F32>(Us, tid);
  Us_l[tid + 256] = ldv<F32>(Us, tid + 256);
  if (tid < 16) {
    const int gi = r0 + tid;
    if (gi < TB) { wl[tid] = wid[gi]; bl[tid] = gi % Bb; tgl[tid] = (float)dirs[gi]; }
    else { const int j = gi - TB; wl[tid] = root_wid[j]; bl[tid] = j; tgl[tid] = 0.f; }
  }
  if (tid < 128) {
    const int rr = tid >> 3, jj = tid & 7;
    const int gi = r0 + rr;
    idsl[tid] = (gi < TB) ? oni[(long)gi * MAXNB + jj]
                          : roni[(long)(gi - TB) * MAXNB + jj];
  }
  __syncthreads();

  {
    const int rr = tid >> 4;   // 0..15
    const int c16 = tid & 15;
    const int wv_ = wl[rr], bv_ = bl[rr];
    for (int g = c16; g < 136; g += 16) {
      const int c8 = g * 8;
      int4 t;
      unsigned short* o = (unsigned short*)&t;
      if (c8 < 512) {
        if (F32) {
          const float* p = (const float*)emb + (long)wv_ * Hh + c8;
          const float4 a = *(const float4*)p, b = *(const float4*)(p + 4);
          o[0] = f2bfu(a.x); o[1] = f2bfu(a.y); o[2] = f2bfu(a.z); o[3] = f2bfu(a.w);
          o[4] = f2bfu(b.x); o[5] = f2bfu(b.y); o[6] = f2bfu(b.z); o[7] = f2bfu(b.w);
        } else {
          t = *(const int4*)((const bf16*)emb + (long)wv_ * Hh + c8);
        }
      } else if (c8 < 1024) {
        const int cc = c8 - 512;
        float s[8] = {0, 0, 0, 0, 0, 0, 0, 0};
        for (int j = 0; j < MAXNB; ++j) {
          const int id = idsl[rr * MAXNB + j];
          const int4 d = *(const int4*)(hbuf + (long)id * Hh + cc);
          const unsigned short* u = (const unsigned short*)&d;
#pragma unroll
          for (int e = 0; e < 8; ++e) s[e] += bfu(u[e]);
        }
#pragma unroll
        for (int e = 0; e < 8; ++e) o[e] = f2bfu(s[e]);
      } else {
        if (F32) {
          const float* p = (const float*)mol_vec + (long)bv_ * Ll + (c8 - 1024);
          const float4 a = *(const float4*)p, b = *(const float4*)(p + 4);
          o[0] = f2bfu(a.x); o[1] = f2bfu(a.y); o[2] = f2bfu(a.z); o[3] = f2bfu(a.w);
          o[4] = f2bfu(b.x); o[5] = f2bfu(b.y); o[6] = f2bfu(b.z); o[7] = f2bfu(b.w);
        } else {
          t = *(const int4*)((const bf16*)mol_vec + (long)bv_ * Ll + (c8 - 1024));
        }
      }
      *(int4*)&As[rr * KUP + c8] = t;
    }
  }
  __syncthreads();

  const int nq = w;
  const int arow = l & 15;
  const int kofs = (l >> 4) * 8;
  f32x4 acc[8];
#pragma unroll
  for (int f = 0; f < 8; ++f) acc[f] = (f32x4){0.f, 0.f, 0.f, 0.f};
  for (int k0 = 0; k0 < KU; k0 += 32) {
    const bf16x8 a = *(const bf16x8*)&As[arow * KUP + k0 + kofs];
    const bf16* bkb = wtU + ((long)(k0 >> 5) * NT_U + nq * 8) * 512 + l * 8;
#pragma unroll
    for (int f = 0; f < 8; ++f) {
      const bf16x8 b = *(const bf16x8*)(bkb + f * 512);
      acc[f] = __builtin_amdgcn_mfma_f32_16x16x32_bf16(a, b, acc[f], 0, 0, 0);
    }
  }

  float ps[4] = {0.f, 0.f, 0.f, 0.f};
#pragma unroll
  for (int f = 0; f < 8; ++f) {
    const int col = nq * 128 + f * 16 + (l & 15);
    const float bu = bU_l[col], us = Us_l[col];
#pragma unroll
    for (int r = 0; r < 4; ++r)
      ps[r] += fmaxf(acc[f][r] + bu, 0.f) * us;
  }
#pragma unroll
  for (int m = 1; m < 16; m <<= 1) {
#pragma unroll
    for (int r = 0; r < 4; ++r) ps[r] += __shfl_xor(ps[r], m, 64);
  }
  if ((l & 15) == 0) {
#pragma unroll
    for (int r = 0; r < 4; ++r)
      sred[((l >> 4) * 4 + r) * 4 + nq] = ps[r];
  }
  __syncthreads();

  if (tid < 16) {
    float s = sred[tid * 4] + sred[tid * 4 + 1] + sred[tid * 4 + 2] +
              sred[tid * 4 + 3] + ldv<F32>(bs, 0);
    const float tg = tgl[tid];
    float loss = fmaxf(s, 0.f) - s * tg + log1pf(expf(-fabsf(s)));
    float ok = ((s >= 0.5f) == (tg > 0.5f)) ? 1.f : 0.f;
#pragma unroll
    for (int m = 1; m < 16; m <<= 1) {
      loss += __shfl_xor(loss, m, 64);
      ok += __shfl_xor(ok, m, 64);
    }
    if (tid == 0) {
      atomicAdd(&accum[0], loss);
      atomicAdd(&accum[1], ok);
    }
  }
}

__global__ __launch_bounds__(256) void stop_mfma(
    const void* mol_vec, const int* __restrict__ wid,
    const int* __restrict__ dirs, const int* __restrict__ oni,
    const int* __restrict__ root_wid, const int* __restrict__ roni,
    const void* emb, const bf16* __restrict__ wtU, const void* bU,
    const void* Us, const void* bs, const bf16* __restrict__ hbuf,
    float* accum, const int* __restrict__ flag) {
  __shared__ __align__(16) unsigned short As[16 * KUP];  // 35 KB
  __shared__ float bU_l[Hh];
  __shared__ float Us_l[Hh];
  __shared__ int   wl[16];
  __shared__ int   bl[16];
  __shared__ float tgl[16];
  __shared__ int   idsl[16 * MAXNB];
  __shared__ float sred[16 * 4];
  if (*flag)
    stop_mfma_body<true>(mol_vec, wid, dirs, oni, root_wid, roni, emb, wtU,
                         bU, Us, bs, hbuf, accum, As, bU_l, Us_l, wl, bl, tgl,
                         idsl, sred);
  else
    stop_mfma_body<false>(mol_vec, wid, dirs, oni, root_wid, roni, emb, wtU,
                          bU, Us, bs, hbuf, accum, As, bU_l, Us_l, wl, bl,
                          tgl, idsl, sred);
}

// ===========================================================================
// MFMA pred head, BM=16 / 256 threads / grid NROWS/16, tiled-B loads.
// (R11-proven, unchanged.)
// ===========================================================================
template <bool F32>
__device__ void pred_mfma_body(
    const void* mol_vec, const int* y_wid, const int* dirs,
    const int* root_wid, const bf16* __restrict__ wtW, const void* bW,
    const bf16* __restrict__ wtWo, const void* bo,
    const bf16* __restrict__ hbuf, float* accum, unsigned short* As1,
    unsigned short* hidl, float* bW_l, float* bo_l, float* maxw, int* idxw,
    float* sumw, float* gmaxl, int* gidxl, float* sbl, int* tgtl,
    float* mskl) {
  const int tid = threadIdx.x;
  const int l = tid & 63, w = tid >> 6;  // w: 0..3
  const int r0 = blockIdx.x * 16;

  bW_l[tid] = ldv<F32>(bW, tid);
  bW_l[tid + 256] = ldv<F32>(bW, tid + 256);
  bo_l[tid] = ldv<F32>(bo, tid);
  bo_l[tid + 256] = ldv<F32>(bo, tid + 256);
  bo_l[tid + 512] = ldv<F32>(bo, tid + 512);
  bo_l[tid + 768] = ldv<F32>(bo, tid + 768);
  if (tid < 16) {
    const int gi = r0 + tid;
    if (gi < Bb) { tgtl[tid] = root_wid[gi]; mskl[tid] = 1.f; }
    else { tgtl[tid] = y_wid[gi - Bb]; mskl[tid] = (float)dirs[gi - Bb]; }
  }
  __syncthreads();

  {
    const int rr = tid >> 4;   // 0..15
    const int c16 = tid & 15;
    const int gi = r0 + rr;
    const int bv_ = (gi < Bb) ? gi : (gi - Bb) % Bb;
    for (int g = c16; g < 72; g += 16) {
      const int c8 = g * 8;
      int4 t;
      unsigned short* o = (unsigned short*)&t;
      if (c8 < 512) {
        if (gi < Bb) t = make_int4(0, 0, 0, 0);
        else t = *(const int4*)(hbuf + (long)(gi - Bb) * Hh + c8);
      } else {
        if (F32) {
          const float* p = (const float*)mol_vec + (long)bv_ * Ll + (c8 - 512);
          const float4 a = *(const float4*)p, b = *(const float4*)(p + 4);
          o[0] = f2bfu(a.x); o[1] = f2bfu(a.y); o[2] = f2bfu(a.z); o[3] = f2bfu(a.w);
          o[4] = f2bfu(b.x); o[5] = f2bfu(b.y); o[6] = f2bfu(b.z); o[7] = f2bfu(b.w);
        } else {
          t = *(const int4*)((const bf16*)mol_vec + (long)bv_ * Ll + (c8 - 512));
        }
      }
      *(int4*)&As1[rr * KWP + c8] = t;
    }
  }
  __syncthreads();

  const int nq = w;
  const int arow = l & 15;
  const int kofs = (l >> 4) * 8;

  // ---- L1: hid = relu(A1 @ W + bW), tiled-B ----
  {
    f32x4 acc1[8];
#pragma unroll
    for (int f = 0; f < 8; ++f) acc1[f] = (f32x4){0.f, 0.f, 0.f, 0.f};
    for (int k0 = 0; k0 < KW; k0 += 32) {
      const bf16x8 a = *(const bf16x8*)&As1[arow * KWP + k0 + kofs];
      const bf16* bkb = wtW + ((long)(k0 >> 5) * NT_U + nq * 8) * 512 + l * 8;
#pragma unroll
      for (int f = 0; f < 8; ++f) {
        const bf16x8 b = *(const bf16x8*)(bkb + f * 512);
        acc1[f] = __builtin_amdgcn_mfma_f32_16x16x32_bf16(a, b, acc1[f], 0, 0, 0);
      }
    }
#pragma unroll
    for (int f = 0; f < 8; ++f) {
      const int col = nq * 128 + f * 16 + (l & 15);
      const float bw = bW_l[col];
#pragma unroll
      for (int r = 0; r < 4; ++r) {
        const int row = (l >> 4) * 4 + r;
        hidl[row * HP + col] = f2bfu(fmaxf(acc1[f][r] + bw, 0.f));
      }
    }
  }
  __syncthreads();

  // ---- L2: logits = hid @ Wo + bo (kept in registers), tiled-B ----
  f32x4 acc2[16];
#pragma unroll
  for (int f = 0; f < 16; ++f) acc2[f] = (f32x4){0.f, 0.f, 0.f, 0.f};
  for (int k0 = 0; k0 < Hh; k0 += 32) {
    const bf16x8 a = *(const bf16x8*)&hidl[arow * HP + k0 + kofs];
    const bf16* bkb = wtWo + ((long)(k0 >> 5) * NT_WO + nq * 16) * 512 + l * 8;
#pragma unroll
    for (int f = 0; f < 16; ++f) {
      const bf16x8 b = *(const bf16x8*)(bkb + f * 512);
      acc2[f] = __builtin_amdgcn_mfma_f32_16x16x32_bf16(a, b, acc2[f], 0, 0, 0);
    }
  }

  // ---- CE: pass A (max/argmax) ----
  float vmax[4]; int vidx[4];
#pragma unroll
  for (int r = 0; r < 4; ++r) { vmax[r] = -3.4e38f; vidx[r] = 0; }
#pragma unroll
  for (int f = 0; f < 16; ++f) {
    const int col = nq * 256 + f * 16 + (l & 15);
    const float bv = bo_l[col];
#pragma unroll
    for (int r = 0; r < 4; ++r) {
      const float v = acc2[f][r] + bv;
      if (v > vmax[r]) { vmax[r] = v; vidx[r] = col; }
    }
  }
#pragma unroll
  for (int m = 1; m < 16; m <<= 1) {
#pragma unroll
    for (int r = 0; r < 4; ++r) {
      const float om = __shfl_xor(vmax[r], m, 64);
      const int oi = __shfl_xor(vidx[r], m, 64);
      if (om > vmax[r] || (om == vmax[r] && oi < vidx[r])) {
        vmax[r] = om; vidx[r] = oi;
      }
    }
  }
  if ((l & 15) == 0) {
#pragma unroll
    for (int r = 0; r < 4; ++r) {
      const int row = (l >> 4) * 4 + r;
      maxw[row * 4 + nq] = vmax[r];
      idxw[row * 4 + nq] = vidx[r];
    }
  }
  __syncthreads();
  if (tid < 16) {
    float gm = -3.4e38f; int gidx = 0;
    for (int q = 0; q < 4; ++q) {
      const float v = maxw[tid * 4 + q];
      const int i2 = idxw[tid * 4 + q];
      if (v > gm || (v == gm && i2 < gidx)) { gm = v; gidx = i2; }
    }
    gmaxl[tid] = gm; gidxl[tid] = gidx;
  }
  __syncthreads();

  // ---- CE: pass B (sum-exp + target logit) ----
  float se[4] = {0.f, 0.f, 0.f, 0.f};
#pragma unroll
  for (int f = 0; f < 16; ++f) {
    const int col = nq * 256 + f * 16 + (l & 15);
    const float bv = bo_l[col];
#pragma unroll
    for (int r = 0; r < 4; ++r) {
      const int row = (l >> 4) * 4 + r;
      const float v = acc2[f][r] + bv;
      se[r] += __expf(v - gmaxl[row]);
      if (col == tgtl[row]) sbl[row] = v;
    }
  }
#pragma unroll
  for (int m = 1; m < 16; m <<= 1) {
#pragma unroll
    for (int r = 0; r < 4; ++r) se[r] += __shfl_xor(se[r], m, 64);
  }
  if ((l & 15) == 0) {
#pragma unroll
    for (int r = 0; r < 4; ++r)
      sumw[((l >> 4) * 4 + r) * 4 + nq] = se[r];
  }
  __syncthreads();

  if (tid < 16) {
    const float ssum = sumw[tid * 4] + sumw[tid * 4 + 1] + sumw[tid * 4 + 2] +
                       sumw[tid * 4 + 3];
    const float lse = gmaxl[tid] + __logf(ssum);
    const float msk = mskl[tid];
    float pl = (lse - sbl[tid]) * msk;
    float pn = (gidxl[tid] == tgtl[tid]) ? msk : 0.f;
    float pm = msk;
#pragma unroll
    for (int m = 1; m < 16; m <<= 1) {
      pl += __shfl_xor(pl, m, 64);
      pn += __shfl_xor(pn, m, 64);
      pm += __shfl_xor(pm, m, 64);
    }
    if (tid == 0) {
      atomicAdd(&accum[2], pl);
      atomicAdd(&accum[3], pn);
      atomicAdd(&accum[4], pm);
    }
  }
}

__global__ __launch_bounds__(256) void pred_mfma(
    const void* mol_vec, const int* __restrict__ y_wid,
    const int* __restrict__ dirs, const int* __restrict__ root_wid,
    const bf16* __restrict__ wtW, const void* bW,
    const bf16* __restrict__ wtWo, const void* bo,
    const bf16* __restrict__ hbuf, float* accum,
    const int* __restrict__ flag) {
  __shared__ __align__(16) unsigned short As1[16 * KWP];   // 18.7 KB
  __shared__ __align__(16) unsigned short hidl[16 * HP];   // 16.6 KB
  __shared__ float bW_l[Hh];
  __shared__ float bo_l[Vv];
  __shared__ float maxw[16 * 4];
  __shared__ int   idxw[16 * 4];
  __shared__ float sumw[16 * 4];
  __shared__ float gmaxl[16];
  __shared__ int   gidxl[16];
  __shared__ float sbl[16];
  __shared__ int   tgtl[16];
  __shared__ float mskl[16];
  if (*flag)
    pred_mfma_body<true>(mol_vec, y_wid, dirs, root_wid, wtW, bW, wtWo, bo,
                         hbuf, accum, As1, hidl, bW_l, bo_l, maxw, idxw, sumw,
                         gmaxl, gidxl, sbl, tgtl, mskl);
  else
    pred_mfma_body<false>(mol_vec, y_wid, dirs, root_wid, wtW, bW, wtWo, bo,
                          hbuf, accum, As1, hidl, bW_l, bo_l, maxw, idxw,
                          sumw, gmaxl, gidxl, sbl, tgtl, mskl);
}

// ---------------------------------------------------------------------------
// VALU heads (fallback when workspace too small for MFMA buffers).
// ---------------------------------------------------------------------------
template <bool F32>
__device__ void stop_body(const void* mol_vec, const int* wid,
                          const int* dirs, const int* oni,
                          const int* root_wid, const int* roni,
                          const void* emb, const void* U, const void* bU,
                          const void* Us, const void* bs, const bf16* hbuf,
                          float* accum,
                          float (*srow)[2 * Hh + Ll], float (*red)[256],
                          float* fin) {
  const int tid = threadIdx.x;
  const int i0 = blockIdx.x * 8;
  const int K = 2 * Hh + Ll;  // 1088

  for (int r = 0; r < 8; ++r) {
    int i = i0 + r;
    int w, b;
    const int* ids;
    if (i < TB) { w = wid[i]; b = i % Bb; ids = &oni[(long)i * MAXNB]; }
    else { int j = i - TB; w = root_wid[j]; b = j; ids = &roni[(long)j * MAXNB]; }
    for (int c = tid; c < K; c += 256) {
      float v;
      if (c < Hh) v = ldv<F32>(emb, (long)w * Hh + c);
      else if (c < 2 * Hh) {
        int cc = c - Hh;
        float s = 0.f;
        for (int j = 0; j < MAXNB; ++j) s += b2f(hbuf[(long)ids[j] * Hh + cc]);
        v = s;
      } else v = ldv<F32>(mol_vec, (long)b * Ll + (c - 2 * Hh));
      srow[r][c] = v;
    }
  }
  __syncthreads();

  const int k0 = tid, k1 = tid + 256;
  float acc[8][2] = {};
  for (int kk = 0; kk < K; ++kk) {
    float u0 = ldv<F32>(U, (long)kk * Hh + k0);
    float u1 = ldv<F32>(U, (long)kk * Hh + k1);
#pragma unroll
    for (int r = 0; r < 8; ++r) {
      float a = srow[r][kk];
      acc[r][0] += a * u0; acc[r][1] += a * u1;
    }
  }
  float bU0 = ldv<F32>(bU, k0), bU1 = ldv<F32>(bU, k1);
  float us0 = ldv<F32>(Us, k0), us1 = ldv<F32>(Us, k1);
  __syncthreads();
#pragma unroll
  for (int r = 0; r < 8; ++r)
    red[r][tid] = fmaxf(acc[r][0] + bU0, 0.f) * us0 + fmaxf(acc[r][1] + bU1, 0.f) * us1;
  __syncthreads();
  for (int off = 128; off; off >>= 1) {
    if (tid < off) {
#pragma unroll
      for (int r = 0; r < 8; ++r) red[r][tid] += red[r][tid + off];
    }
    __syncthreads();
  }
  if (tid < 8) {
    int i = i0 + tid;
    float s = red[tid][0] + ldv<F32>(bs, 0);
    float tgt = (i < TB) ? (float)dirs[i] : 0.f;
    float loss = fmaxf(s, 0.f) - s * tgt + log1pf(expf(-fabsf(s)));
    float ok = ((s >= 0.5f) == (tgt > 0.5f)) ? 1.f : 0.f;
    fin[tid] = loss; fin[8 + tid] = ok;
  }
  __syncthreads();
  if (tid == 0) {
    float ls = 0.f, oks = 0.f;
    for (int r = 0; r < 8; ++r) { ls += fin[r]; oks += fin[8 + r]; }
    atomicAdd(&accum[0], ls);
    atomicAdd(&accum[1], oks);
  }
}

__global__ __launch_bounds__(256) void stop_kernel(
    const void* mol_vec, const int* __restrict__ wid,
    const int* __restrict__ dirs, const int* __restrict__ oni,
    const int* __restrict__ root_wid, const int* __restrict__ roni,
    const void* emb, const void* U, const void* bU, const void* Us,
    const void* bs, const bf16* hbuf, float* accum,
    const int* __restrict__ flag) {
  __shared__ float srow[8][2 * Hh + Ll];
  __shared__ float red[8][256];
  __shared__ float fin[16];
  if (*flag)
    stop_body<true>(mol_vec, wid, dirs, oni, root_wid, roni, emb, U, bU, Us,
                    bs, hbuf, accum, srow, red, fin);
  else
    stop_body<false>(mol_vec, wid, dirs, oni, root_wid, roni, emb, U, bU, Us,
                     bs, hbuf, accum, srow, red, fin);
}

template <bool F32>
__device__ void pred_body(const void* mol_vec, const int* y_wid,
                          const int* dirs, const int* root_wid, const void* W,
                          const void* bW, const void* Wo, const void* bo,
                          const bf16* hbuf, float* accum,
                          float (*srow)[Hh + Ll], float (*hid)[Hh],
                          float* rv, int* ri, float* sb) {
  const int tid = threadIdx.x;
  const int i0 = blockIdx.x * 8;
  const int K1 = Hh + Ll;  // 576

  for (int r = 0; r < 8; ++r) {
    int i = i0 + r;
    int b = (i < Bb) ? i : (i - Bb) % Bb;
    for (int c = tid; c < K1; c += 256) {
      float v;
      if (c < Hh) v = (i < Bb) ? 0.f : b2f(hbuf[(long)(i - Bb) * Hh + c]);
      else v = ldv<F32>(mol_vec, (long)b * Ll + (c - Hh));
      srow[r][c] = v;
    }
  }
  __syncthreads();

  const int k0 = tid, k1 = tid + 256;
  float acc[8][2] = {};
  for (int kk = 0; kk < K1; ++kk) {
    float w0 = ldv<F32>(W, (long)kk * Hh + k0);
    float w1 = ldv<F32>(W, (long)kk * Hh + k1);
#pragma unroll
    for (int r = 0; r < 8; ++r) {
      float a = srow[r][kk];
      acc[r][0] += a * w0; acc[r][1] += a * w1;
    }
  }
  float bW0 = ldv<F32>(bW, k0), bW1 = ldv<F32>(bW, k1);
#pragma unroll
  for (int r = 0; r < 8; ++r) {
    hid[r][k0] = fmaxf(acc[r][0] + bW0, 0.f);
    hid[r][k1] = fmaxf(acc[r][1] + bW1, 0.f);
  }
  __syncthreads();

  float lg[8][4] = {};
  for (int kk = 0; kk < Hh; ++kk) {
    float w0 = ldv<F32>(Wo, (long)kk * Vv + tid);
    float w1 = ldv<F32>(Wo, (long)kk * Vv + tid + 256);
    float w2 = ldv<F32>(Wo, (long)kk * Vv + tid + 512);
    float w3 = ldv<F32>(Wo, (long)kk * Vv + tid + 768);
#pragma unroll
    for (int r = 0; r < 8; ++r) {
      float a = hid[r][kk];
      lg[r][0] += a * w0; lg[r][1] += a * w1;
      lg[r][2] += a * w2; lg[r][3] += a * w3;
    }
  }
  float bo0 = ldv<F32>(bo, tid);
  float bo1 = ldv<F32>(bo, tid + 256);
  float bo2 = ldv<F32>(bo, tid + 512);
  float bo3 = ldv<F32>(bo, tid + 768);

  float plloss = 0.f, pnum = 0.f, pmask = 0.f;
  for (int r = 0; r < 8; ++r) {
    int i = i0 + r;
    int tgt = (i < Bb) ? root_wid[i] : y_wid[i - Bb];
    float msk = (i < Bb) ? 1.f : (float)dirs[i - Bb];
    float v0 = lg[r][0] + bo0, v1 = lg[r][1] + bo1;
    float v2 = lg[r][2] + bo2, v3 = lg[r][3] + bo3;

    float bm = v0; int bi = tid;
    if (v1 > bm) { bm = v1; bi = tid + 256; }
    if (v2 > bm) { bm = v2; bi = tid + 512; }
    if (v3 > bm) { bm = v3; bi = tid + 768; }
    rv[tid] = bm; ri[tid] = bi;
    if ((tgt & 255) == tid) {
      int cc = tgt >> 8;
      sb[0] = (cc == 0) ? v0 : (cc == 1) ? v1 : (cc == 2) ? v2 : v3;
    }
    __syncthreads();
    for (int off = 128; off; off >>= 1) {
      if (tid < off) {
        float o = rv[tid + off]; int oi = ri[tid + off];
        if (o > rv[tid] || (o == rv[tid] && oi < ri[tid])) { rv[tid] = o; ri[tid] = oi; }
      }
      __syncthreads();
    }
    float m = rv[0];
    int am = ri[0];
    __syncthreads();
    rv[tid] = __expf(v0 - m) + __expf(v1 - m) + __expf(v2 - m) + __expf(v3 - m);
    __syncthreads();
    for (int off = 128; off; off >>= 1) {
      if (tid < off) rv[tid] += rv[tid + off];
      __syncthreads();
    }
    if (tid == 0) {
      float lse = m + __logf(rv[0]);
      float ce = lse - sb[0];
      plloss += ce * msk;
      pnum += (am == tgt) ? msk : 0.f;
      pmask += msk;
    }
    __syncthreads();
  }
  if (tid == 0) {
    atomicAdd(&accum[2], plloss);
    atomicAdd(&accum[3], pnum);
    atomicAdd(&accum[4], pmask);
  }
}

__global__ __launch_bounds__(256) void pred_kernel(
    const void* mol_vec, const int* __restrict__ y_wid,
    const int* __restrict__ dirs, const int* __restrict__ root_wid,
    const void* W, const void* bW, const void* Wo, const void* bo,
    const bf16* hbuf, float* accum, const int* __restrict__ flag) {
  __shared__ float srow[8][Hh + Ll];
  __shared__ float hid[8][Hh];
  __shared__ float rv[256];
  __shared__ int   ri[256];
  __shared__ float sb[2];
  if (*flag)
    pred_body<true>(mol_vec, y_wid, dirs, root_wid, W, bW, Wo, bo, hbuf,
                    accum, srow, hid, rv, ri, sb);
  else
    pred_body<false>(mol_vec, y_wid, dirs, root_wid, W, bW, Wo, bo, hbuf,
                     accum, srow, hid, rv, ri, sb);
}

__global__ void finalize_kernel(const float* __restrict__ accum,
                                const int* __restrict__ flag, void* out) {
  if (threadIdx.x == 0 && blockIdx.x == 0) {
    float o0 = accum[2] / (float)Bb;      // pred_loss
    float o1 = accum[0] / (float)Bb;      // stop_loss
    float o2 = accum[3] / accum[4];       // pred_acc
    float o3 = accum[1] / (float)NROWS;   // stop_acc
    if (*flag) {
      float* o = (float*)out;
      o[0] = o0; o[1] = o1; o[2] = o2; o[3] = o3;
    } else {
      bf16* o = (bf16*)out;
      o[0] = __float2bfloat16(o0); o[1] = __float2bfloat16(o1);
      o[2] = __float2bfloat16(o2); o[3] = __float2bfloat16(o3);
    }
  }
}

extern "C" void kernel_launch(void* const* d_in, const int* in_sizes, int n_in,
                              void* d_out, int out_size, void* d_ws, size_t ws_size,
                              hipStream_t stream) {
  const void* mol_vec  = d_in[0];
  const int*  wid      = (const int*)d_in[1];
  const int*  y_wid    = (const int*)d_in[2];
  const int*  dirs     = (const int*)d_in[3];
  const int*  hni      = (const int*)d_in[4];
  const int*  oni      = (const int*)d_in[5];
  const int*  root_wid = (const int*)d_in[6];
  const int*  roni     = (const int*)d_in[7];
  const void* emb      = d_in[8];
  const void* Wz       = d_in[9];
  const void* bz       = d_in[10];
  const void* Wr       = d_in[11];
  const void* br       = d_in[12];
  const void* Ur       = d_in[13];
  const void* Wh       = d_in[14];
  const void* bh       = d_in[15];
  const void* W        = d_in[16];
  const void* bW       = d_in[17];
  const void* U        = d_in[18];
  const void* bU       = d_in[19];
  const void* Wo       = d_in[20];
  const void* bo       = d_in[21];
  const void* Us       = d_in[22];
  const void* bs       = d_in[23];

  // ws: [accum 8f][flag 1i][pad->64B][hbuf][xproj][wtW][wtU][wtWo][wgZ][wgR][wgH2]
  float* accum = (float*)d_ws;
  int*   flag  = (int*)d_ws + 8;
  bf16*  hbuf  = (bf16*)((char*)d_ws + 64);
  bf16*  xproj = hbuf + (long)(TB + 1) * Hh;
  bf16*  wtW   = xproj + (long)Vv * XPS;
  bf16*  wtU   = wtW + (long)Hh * KW;
  bf16*  wtWo  = wtU + (long)Hh * KU;
  bf16*  wgZ   = wtWo + (long)Vv * Hh;
  bf16*  wgR   = wgZ + (long)Hh * Hh;
  bf16*  wgH2  = wgR + (long)Hh * Hh;

  const size_t need_xp = 64 + ((size_t)(TB + 1) * Hh + (size_t)Vv * XPS) * sizeof(bf16);
  const size_t need_m  = need_xp +
      ((size_t)Hh * KW + (size_t)Hh * KU + (size_t)Vv * Hh) * sizeof(bf16);
  const size_t need_g  = need_m + 3ull * Hh * Hh * sizeof(bf16);
  const bool use_xp = (ws_size >= need_xp);  // constant across calls: graph-safe
  const bool useM   = (ws_size >= need_m);
  const bool useG   = (ws_size >= need_g);

  hipMemsetAsync(d_ws, 0, 64, stream);                                   // accum+flag
  hipMemsetAsync(hbuf + (long)TB * Hh, 0, Hh * sizeof(bf16), stream);    // PAD row

  detect_kernel<<<64, 256, 0, stream>>>((const unsigned short*)emb, flag);

  if (useM) {
    const int nblk = useG ? 528 : 336;  // +192 tiles for wgZ/wgR/wgH2
    wt_kernel<<<nblk, 256, 0, stream>>>(W, U, Wo, Wz, Ur, Wh, wtW, wtU, wtWo,
                                        wgZ, wgR, wgH2, flag);
  }
  if (use_xp) {
    xproj_kernel<<<Vv, 512, 0, stream>>>(emb, Wz, bz, Wr, br, Wh, bh, xproj, flag);
    if (useG) {
      for (int t = 0; t < Tt; ++t) {
        gru_step_xpb<<<Bb / 4, 512, 0, stream>>>(t, wid, hni, xproj, wgZ, wgR,
                                                 wgH2, hbuf);
      }
    } else {
      for (int t = 0; t < Tt; ++t) {
        gru_step_xp<<<Bb / 2, 512, 0, stream>>>(t, wid, hni, xproj, Wz, Ur,
                                                Wh, hbuf, flag);
      }
    }
  } else {
    for (int t = 0; t < Tt; ++t) {
      gru_step<<<Bb / 2, 512, 0, stream>>>(t, wid, hni, emb, Wz, bz, Wr, br,
                                           Ur, Wh, bh, hbuf, flag);
    }
  }

  if (useM) {
    stop_mfma<<<NROWS / 16, 256, 0, stream>>>(mol_vec, wid, dirs, oni,
                                              root_wid, roni, emb, wtU, bU, Us,
                                              bs, hbuf, accum, flag);
    pred_mfma<<<NROWS / 16, 256, 0, stream>>>(mol_vec, y_wid, dirs, root_wid,
                                              wtW, bW, wtWo, bo, hbuf, accum,
                                              flag);
  } else {
    stop_kernel<<<NROWS / 8, 256, 0, stream>>>(mol_vec, wid, dirs, oni,
                                               root_wid, roni, emb, U, bU, Us,
                                               bs, hbuf, accum, flag);
    pred_kernel<<<NROWS / 8, 256, 0, stream>>>(mol_vec, y_wid, dirs, root_wid,
                                               W, bW, Wo, bo, hbuf, accum,
                                               flag);
  }
  finalize_kernel<<<1, 64, 0, stream>>>(accum, flag, d_out);
}

// Round 17
// 1768.489 us; speedup vs baseline: 1.1845x; 1.1845x over previous
//
#include <hip/hip_runtime.h>
#include <hip/hip_bf16.h>

typedef __hip_bfloat16 bf16;
typedef __attribute__((ext_vector_type(8))) short bf16x8;
typedef __attribute__((ext_vector_type(4))) float f32x4;

static constexpr int Bb = 512;
static constexpr int Hh = 512;
static constexpr int Ll = 64;
static constexpr int Vv = 1024;
static constexpr int MAXNB = 8;
static constexpr int Tt = 46;          // 2*(N-1)
static constexpr int TB = Tt * Bb;     // 23552, also PAD index
static constexpr int PADID = TB;
static constexpr int NROWS = TB + Bb;  // 24064
static constexpr int XPS = 3 * Hh;     // xproj row stride (bf16 elems)

// MFMA head geometry (BM=16 tiles)
static constexpr int KU  = 2 * Hh + Ll;  // 1088 (stop K)
static constexpr int KUP = KU + 8;       // 1096 padded
static constexpr int KW  = Hh + Ll;      // 576 (pred L1 K)
static constexpr int KWP = KW + 8;       // 584 padded
static constexpr int HP  = Hh + 8;       // 520 padded hid stride

// tiled-weight col-tile counts (N/16)
static constexpr int NT_U  = Hh / 16;    // 32 (N=512 weights)
static constexpr int NT_WO = Vv / 16;    // 64 (wtWo: N=1024)

__device__ __forceinline__ float b2f(bf16 v) { return __bfloat162float(v); }
__device__ __forceinline__ float sigm(float x) { return 1.f / (1.f + __expf(-x)); }
__device__ __forceinline__ float bfu(unsigned short u) {
  return __uint_as_float((unsigned)u << 16);
}
__device__ __forceinline__ unsigned short f2bfu(float x) {
  bf16 v = __float2bfloat16(x);
  return *(unsigned short*)&v;
}

// dtype-adaptive load: F32 ? fp32 tensor : bf16 tensor
template <bool F32>
__device__ __forceinline__ float ldv(const void* p, long i) {
  if (F32) return ((const float*)p)[i];
  return __bfloat162float(((const bf16*)p)[i]);
}

// ---------------------------------------------------------------------------
// dtype probe
// ---------------------------------------------------------------------------
__global__ void detect_kernel(const unsigned short* __restrict__ embu,
                              int* __restrict__ flag) {
  const long n = (long)Vv * Hh;
  int bad = 0;
  for (long i = blockIdx.x * 256 + threadIdx.x; i < n; i += 256L * 64) {
    unsigned short u = embu[i];
    if ((u & 0x7F80u) == 0x7F80u) bad = 1;
  }
  if (bad) atomicOr(flag, 1);
}

// ---------------------------------------------------------------------------
// xproj[v] = [emb[v]@Wz[:H]+bz | emb[v]@Wr+br | emb[v]@Wh[:H]+bh], bf16 out.
// ---------------------------------------------------------------------------
template <bool F32>
__device__ void xproj_body(const void* emb, const void* Wz, const void* bz,
                           const void* Wr, const void* br, const void* Wh,
                           const void* bh, bf16* xproj, float* xe) {
  const int v = blockIdx.x, k = threadIdx.x;
  xe[k] = ldv<F32>(emb, (long)v * Hh + k);
  __syncthreads();
  float z = ldv<F32>(bz, k);
  float r = ldv<F32>(br, k);
  float h = ldv<F32>(bh, k);
  for (int i = 0; i < Hh; ++i) {
    float a = xe[i];
    z += a * ldv<F32>(Wz, (long)i * Hh + k);
    r += a * ldv<F32>(Wr, (long)i * Hh + k);
    h += a * ldv<F32>(Wh, (long)i * Hh + k);
  }
  bf16* xp = xproj + (long)v * XPS;
  xp[k]          = __float2bfloat16(z);
  xp[Hh + k]     = __float2bfloat16(r);
  xp[2 * Hh + k] = __float2bfloat16(h);
}

__global__ __launch_bounds__(512) void xproj_kernel(
    const void* emb, const void* Wz, const void* bz, const void* Wr,
    const void* br, const void* Wh, const void* bh, bf16* xproj,
    const int* __restrict__ flag) {
  __shared__ float xe[Hh];
  if (*flag)
    xproj_body<true>(emb, Wz, bz, Wr, br, Wh, bh, xproj, xe);
  else
    xproj_body<false>(emb, Wz, bz, Wr, br, Wh, bh, xproj, xe);
}

// ---------------------------------------------------------------------------
// Tiled weight transposes, fragment-native layout (R11-proven):
// element (n, k) -> ((k>>5)*NT + (n>>4))*512 + ((k&31)>>3)*128 + (n&15)*8
//                   + (k&7). One wave B-frag = consecutive 1KB.
// ro = source row offset (for Wz/Wh lower halves).
// ---------------------------------------------------------------------------
template <bool F32>
__device__ __forceinline__ void wtt_body(const void* src, bf16* dst, int K,
                                         int N, int NT, int ro, int tk0,
                                         int tn0, unsigned short (*tile)[65]) {
  const int tid = threadIdx.x;
  const int ln = tid & 63;
  const int gr = tid >> 6;  // 0..3
  for (int kk = gr; kk < 64; kk += 4) {
    const int k = tk0 + kk, n = tn0 + ln;
    tile[ln][kk] = f2bfu(ldv<F32>(src, (long)(ro + k) * N + n));
  }
  __syncthreads();
  for (int nn = gr; nn < 64; nn += 4) {
    const int n = tn0 + nn, k = tk0 + ln;
    const long off = ((long)(k >> 5) * NT + (n >> 4)) * 512 +
                     ((k & 31) >> 3) * 128 + (n & 15) * 8 + (k & 7);
    dst[off] = *(bf16*)&tile[nn][ln];
  }
}

__global__ __launch_bounds__(256) void wt_kernel(
    const void* W, const void* U, const void* Wo, const void* Wz,
    const void* Ur, const void* Wh, bf16* wtW, bf16* wtU, bf16* wtWo,
    bf16* wgZ, bf16* wgR, bf16* wgH2, const int* __restrict__ flag) {
  __shared__ unsigned short tile[64][65];
  int b = blockIdx.x;
  const void* src; bf16* dst; int K, N, NT, ro, tk, tn;
  if (b < 72) {            // W: K=576, N=512 -> 9x8 tiles
    src = W; dst = wtW; K = KW; N = Hh; NT = NT_U; ro = 0; tk = b / 8; tn = b % 8;
  } else if (b < 208) {    // U: K=1088, N=512 -> 17x8 tiles
    b -= 72; src = U; dst = wtU; K = KU; N = Hh; NT = NT_U; ro = 0; tk = b / 8; tn = b % 8;
  } else if (b < 336) {    // Wo: K=512, N=1024 -> 8x16 tiles
    b -= 208; src = Wo; dst = wtWo; K = Hh; N = Vv; NT = NT_WO; ro = 0; tk = b / 16; tn = b % 16;
  } else if (b < 400) {    // Wz lower half (rows Hh..2Hh): 8x8 tiles
    b -= 336; src = Wz; dst = wgZ; K = Hh; N = Hh; NT = NT_U; ro = Hh; tk = b / 8; tn = b % 8;
  } else if (b < 464) {    // Ur: 8x8 tiles
    b -= 400; src = Ur; dst = wgR; K = Hh; N = Hh; NT = NT_U; ro = 0; tk = b / 8; tn = b % 8;
  } else {                 // Wh lower half: 8x8 tiles
    b -= 464; src = Wh; dst = wgH2; K = Hh; N = Hh; NT = NT_U; ro = Hh; tk = b / 8; tn = b % 8;
  }
  if (*flag) wtt_body<true>(src, dst, K, N, NT, ro, tk * 64, tn * 64, tile);
  else       wtt_body<false>(src, dst, K, N, NT, ro, tk * 64, tn * 64, tile);
}

// ---------------------------------------------------------------------------
// Shared neighbor-prep for gru variants.
// ---------------------------------------------------------------------------
__device__ __forceinline__ int gru_prep(int t, int b0, const int* hni,
                                        int* cid, int* rowf, int* nvs) {
  const int k = threadIdx.x;
  if (k < 2 * MAXNB)
    cid[k] = hni[((long)t * Bb + b0 + (k >> 3)) * MAXNB + (k & 7)];
  __syncthreads();
  if (k == 0) {
    int n0 = 0; while (n0 < MAXNB && cid[n0] != PADID) ++n0;
    int n1 = 0; while (n1 < MAXNB && cid[MAXNB + n1] != PADID) ++n1;
    for (int j = 0; j < n1; ++j) cid[n0 + j] = cid[MAXNB + j];
    for (int p = 0; p < n0 + n1; ++p) rowf[p] = (p >= n0) ? 1 : 0;
    nvs[0] = n0; nvs[1] = n1;
  }
  __syncthreads();
  return nvs[0] + nvs[1];
}

// ---------------------------------------------------------------------------
// MFMA GEMV phase for the GRU step: out[s][col] = sum_i A[s][i]*Wt[col][i],
// S <= 4 streams, 512 cols, K=512. 8 waves x 64 cols; A rows beyond S are
// zero; B frags are 1KB coalesced (tiled layout). Writes red[s*Hh + col].
//   ABF ? A is bf16 LDS (stride Hh) : A is f32 LDS (stride Hh)
// ---------------------------------------------------------------------------
template <bool ABF, int S>
__device__ __forceinline__ void mfma_gemv(const bf16* __restrict__ Wt,
                                          const void* __restrict__ Abase,
                                          float* __restrict__ red,
                                          int wv, int l) {
  const int arow = l & 15;
  const int kofs = (l >> 4) * 8;
  f32x4 acc[4];
#pragma unroll
  for (int f = 0; f < 4; ++f) acc[f] = (f32x4){0.f, 0.f, 0.f, 0.f};

  for (int k0 = 0; k0 < Hh; k0 += 32) {
    unsigned short av[8] = {0, 0, 0, 0, 0, 0, 0, 0};
    if (arow < S) {
      if (ABF) {
        *(int4*)av = *(const int4*)((const bf16*)Abase + (long)arow * Hh +
                                    k0 + kofs);
      } else {
        const float* s = (const float*)Abase + (long)arow * Hh + k0 + kofs;
#pragma unroll
        for (int e = 0; e < 8; ++e) av[e] = f2bfu(s[e]);
      }
    }
    const bf16x8 a = *(const bf16x8*)av;
    const bf16* bkb = Wt + ((long)(k0 >> 5) * NT_U + wv * 4) * 512 + l * 8;
#pragma unroll
    for (int f = 0; f < 4; ++f) {
      const bf16x8 b = *(const bf16x8*)(bkb + f * 512);
      acc[f] = __builtin_amdgcn_mfma_f32_16x16x32_bf16(a, b, acc[f], 0, 0, 0);
    }
  }
#pragma unroll
  for (int f = 0; f < 4; ++f) {
    const int col = wv * 64 + f * 16 + (l & 15);
#pragma unroll
    for (int r = 0; r < 4; ++r) {
      const int row = (l >> 4) * 4 + r;
      if (row < S) red[row * Hh + col] = acc[f][r];
    }
  }
}

// ---------------------------------------------------------------------------
// GRU scan step, MFMA variant in the PROVEN R8 geometry: 2 mols per block,
// grid 256, 512 threads. GEMVs run on the matrix pipe via mfma_gemv; all
// phase logic / staging / epilogue identical to the proven kernel.
// LDS ~33 KB.
// ---------------------------------------------------------------------------
__global__ __launch_bounds__(512) void gru_step_xpb(
    int t, const int* __restrict__ wid, const int* __restrict__ hni,
    const bf16* __restrict__ xproj, const bf16* __restrict__ wgZ,
    const bf16* __restrict__ wgR, const bf16* __restrict__ wgH2,
    bf16* __restrict__ hbuf) {
  __shared__ float sh[2 * Hh];                                  // 4 KB
  __shared__ float sg[2 * Hh];                                  // 4 KB
  __shared__ __align__(16) unsigned short hnc[2 * MAXNB * Hh];  // 16 KB
  __shared__ float red[4 * Hh];                                 // 8 KB
  __shared__ int   cid[2 * MAXNB];
  __shared__ int   rowf[2 * MAXNB];
  __shared__ int   nvs[2];

  const int tid = threadIdx.x;
  const int k = tid;
  const int wv_ = tid >> 6;
  const int l = tid & 63;
  const int b0 = blockIdx.x * 2;
  const int P = gru_prep(t, b0, hni, cid, rowf, nvs);

  const int w0 = wid[t * Bb + b0];
  const int w1 = wid[t * Bb + b0 + 1];
  const bf16* xp0 = xproj + (long)w0 * XPS;
  const bf16* xp1 = xproj + (long)w1 * XPS;

  // gather neighbor h rows into LDS (bf16, lossless), one wave per pair
  for (int p = wv_; p < P; p += 8) {
    const int4 d = *(const int4*)(hbuf + (long)cid[p] * Hh + 8 * l);
    *(int4*)(hnc + p * Hh + 8 * l) = d;
  }
  __syncthreads();

  float s0 = 0.f, s1 = 0.f;
  for (int p = 0; p < P; ++p) {
    const float hv = __bfloat162float(((const bf16*)hnc)[p * Hh + k]);
    if (rowf[p]) s1 += hv; else s0 += hv;
  }
  sh[k] = s0; sh[Hh + k] = s1;
  const float xz0 = b2f(xp0[k]),          xz1 = b2f(xp1[k]);
  const float xr0 = b2f(xp0[Hh + k]),     xr1 = b2f(xp1[Hh + k]);
  const float xh0 = b2f(xp0[2 * Hh + k]), xh1 = b2f(xp1[2 * Hh + k]);
  __syncthreads();

  // ---- z pre-activation: xz + sum_h @ WzH (MFMA) ----
  mfma_gemv<false, 2>(wgZ, sh, red, wv_, l);
  __syncthreads();
  const float zp0 = xz0 + red[k];
  const float zp1 = xz1 + red[Hh + k];
  __syncthreads();  // red reused below

  // ---- sum_g: chunks of up to 4 pairs through Ur (MFMA) ----
  float g0 = 0.f, g1 = 0.f;
  for (int c = 0; c < P; c += 4) {
    const int ns = (P - c >= 4) ? 4 : (P - c);
    const unsigned short* Ab = hnc + c * Hh;
    switch (ns) {
      case 1: mfma_gemv<true, 1>(wgR, Ab, red, wv_, l); break;
      case 2: mfma_gemv<true, 2>(wgR, Ab, red, wv_, l); break;
      case 3: mfma_gemv<true, 3>(wgR, Ab, red, wv_, l); break;
      default: mfma_gemv<true, 4>(wgR, Ab, red, wv_, l); break;
    }
    __syncthreads();
    for (int q = 0; q < ns; ++q) {
      const int p = c + q;
      const float rp = (rowf[p] ? xr1 : xr0) + red[q * Hh + k];
      const float cc =
          sigm(rp) * __bfloat162float(((const bf16*)hnc)[p * Hh + k]);
      if (rowf[p]) g1 += cc; else g0 += cc;
    }
    __syncthreads();  // red reused next chunk / by h phase
  }
  sg[k] = g0; sg[Hh + k] = g1;
  __syncthreads();

  // ---- h_tilde pre-activation: xh + sum_g @ WhH (MFMA) ----
  mfma_gemv<false, 2>(wgH2, sg, red, wv_, l);
  __syncthreads();
  const float hp0 = xh0 + red[k];
  const float hp1 = xh1 + red[Hh + k];

  float z;
  z = sigm(zp0); const float o0 = (1.f - z) * s0 + z * tanhf(hp0);
  z = sigm(zp1); const float o1 = (1.f - z) * s1 + z * tanhf(hp1);
  hbuf[((long)t * Bb + b0) * Hh + k]     = __float2bfloat16(o0);
  hbuf[((long)t * Bb + b0 + 1) * Hh + k] = __float2bfloat16(o1);
}

// ---------------------------------------------------------------------------
// R1 K-split GEMV phase (proven fallback — do not touch).
// ---------------------------------------------------------------------------
template <bool F32, bool ABF, int S>
__device__ __forceinline__ void gemv_phase(const void* __restrict__ Wp,
                                           long wrow0,
                                           const void* __restrict__ Abase,
                                           float* __restrict__ red,
                                           int kg, int ch0) {
  float acc[S][4];
#pragma unroll
  for (int s = 0; s < S; ++s)
#pragma unroll
    for (int j = 0; j < 4; ++j) acc[s][j] = 0.f;
  const int i0 = kg * 128;
#pragma unroll 4
  for (int ii = 0; ii < 128; ++ii) {
    const int i = i0 + ii;
    float wv[4];
    if (F32) {
      const float4 f =
          *(const float4*)((const float*)Wp + (wrow0 + i) * (long)Hh + ch0);
      wv[0] = f.x; wv[1] = f.y; wv[2] = f.z; wv[3] = f.w;
    } else {
      const uint2 d =
          *(const uint2*)((const bf16*)Wp + (wrow0 + i) * (long)Hh + ch0);
      wv[0] = __uint_as_float(d.x << 16);
      wv[1] = __uint_as_float(d.x & 0xffff0000u);
      wv[2] = __uint_as_float(d.y << 16);
      wv[3] = __uint_as_float(d.y & 0xffff0000u);
    }
#pragma unroll
    for (int s = 0; s < S; ++s) {
      const float a = ABF
          ? __bfloat162float(((const bf16*)Abase)[s * Hh + i])
          : ((const float*)Abase)[s * Hh + i];
#pragma unroll
      for (int j = 0; j < 4; ++j) acc[s][j] += a * wv[j];
    }
  }
#pragma unroll
  for (int s = 0; s < S; ++s)
#pragma unroll
    for (int j = 0; j < 4; ++j)
      red[(kg * 4 + s) * Hh + ch0 + j] = acc[s][j];
}

// ---------------------------------------------------------------------------
// GRU scan step, xproj variant — R1 proven fallback (original weights).
// ---------------------------------------------------------------------------
template <bool F32>
__device__ void gru_body_xp(int t, const int* wid, const int* hni,
                            const bf16* xproj, const void* Wz, const void* Ur,
                            const void* Wh, bf16* hbuf, float* sh, float* sg,
                            unsigned short* hnc, float* red, int* cid,
                            int* rowf, int* nvs) {
  const int tid = threadIdx.x;
  const int k = tid;
  const int wv_ = tid >> 6;
  const int l = tid & 63;
  const int kg = wv_ >> 1;
  const int ch0 = (wv_ & 1) * 256 + l * 4;
  const int b0 = blockIdx.x * 2;
  const int P = gru_prep(t, b0, hni, cid, rowf, nvs);

  const int w0 = wid[t * Bb + b0];
  const int w1 = wid[t * Bb + b0 + 1];
  const bf16* xp0 = xproj + (long)w0 * XPS;
  const bf16* xp1 = xproj + (long)w1 * XPS;

  for (int p = wv_; p < P; p += 8) {
    const int4 d = *(const int4*)(hbuf + (long)cid[p] * Hh + 8 * l);
    *(int4*)(hnc + p * Hh + 8 * l) = d;
  }
  __syncthreads();

  float s0 = 0.f, s1 = 0.f;
  for (int p = 0; p < P; ++p) {
    const float hv = __bfloat162float(((const bf16*)hnc)[p * Hh + k]);
    if (rowf[p]) s1 += hv; else s0 += hv;
  }
  sh[k] = s0; sh[Hh + k] = s1;
  const float xz0 = b2f(xp0[k]),          xz1 = b2f(xp1[k]);
  const float xr0 = b2f(xp0[Hh + k]),     xr1 = b2f(xp1[Hh + k]);
  const float xh0 = b2f(xp0[2 * Hh + k]), xh1 = b2f(xp1[2 * Hh + k]);
  __syncthreads();

  gemv_phase<F32, false, 2>(Wz, Hh, sh, red, kg, ch0);
  __syncthreads();
  float zp0 = xz0, zp1 = xz1;
#pragma unroll
  for (int g = 0; g < 4; ++g) {
    zp0 += red[(g * 4 + 0) * Hh + k];
    zp1 += red[(g * 4 + 1) * Hh + k];
  }
  __syncthreads();

  float g0 = 0.f, g1 = 0.f;
  for (int c = 0; c < P; c += 4) {
    const int ns = (P - c >= 4) ? 4 : (P - c);
    const unsigned short* Ab = hnc + c * Hh;
    switch (ns) {
      case 1: gemv_phase<F32, true, 1>(Ur, 0, Ab, red, kg, ch0); break;
      case 2: gemv_phase<F32, true, 2>(Ur, 0, Ab, red, kg, ch0); break;
      case 3: gemv_phase<F32, true, 3>(Ur, 0, Ab, red, kg, ch0); break;
      default: gemv_phase<F32, true, 4>(Ur, 0, Ab, red, kg, ch0); break;
    }
    __syncthreads();
    for (int q = 0; q < ns; ++q) {
      const int p = c + q;
      float rp = rowf[p] ? xr1 : xr0;
#pragma unroll
      for (int g = 0; g < 4; ++g) rp += red[(g * 4 + q) * Hh + k];
      const float cc =
          sigm(rp) * __bfloat162float(((const bf16*)hnc)[p * Hh + k]);
      if (rowf[p]) g1 += cc; else g0 += cc;
    }
    __syncthreads();
  }
  sg[k] = g0; sg[Hh + k] = g1;
  __syncthreads();

  gemv_phase<F32, false, 2>(Wh, Hh, sg, red, kg, ch0);
  __syncthreads();
  float hp0 = xh0, hp1 = xh1;
#pragma unroll
  for (int g = 0; g < 4; ++g) {
    hp0 += red[(g * 4 + 0) * Hh + k];
    hp1 += red[(g * 4 + 1) * Hh + k];
  }

  float z;
  z = sigm(zp0); const float o0 = (1.f - z) * s0 + z * tanhf(hp0);
  z = sigm(zp1); const float o1 = (1.f - z) * s1 + z * tanhf(hp1);
  hbuf[((long)t * Bb + b0) * Hh + k]     = __float2bfloat16(o0);
  hbuf[((long)t * Bb + b0 + 1) * Hh + k] = __float2bfloat16(o1);
}

__global__ __launch_bounds__(512) void gru_step_xp(
    int t, const int* __restrict__ wid, const int* __restrict__ hni,
    const bf16* xproj, const void* Wz, const void* Ur, const void* Wh,
    bf16* hbuf, const int* __restrict__ flag) {
  __shared__ float sh[2 * Hh];
  __shared__ float sg[2 * Hh];
  __shared__ __align__(16) unsigned short hnc[2 * MAXNB * Hh];
  __shared__ float red[4 * 4 * Hh];
  __shared__ int   cid[2 * MAXNB];
  __shared__ int   rowf[2 * MAXNB];
  __shared__ int   nvs[2];
  if (*flag)
    gru_body_xp<true>(t, wid, hni, xproj, Wz, Ur, Wh, hbuf, sh, sg, hnc, red,
                      cid, rowf, nvs);
  else
    gru_body_xp<false>(t, wid, hni, xproj, Wz, Ur, Wh, hbuf, sh, sg, hnc, red,
                       cid, rowf, nvs);
}

// ---------------------------------------------------------------------------
// Legacy fallback (no xproj buffer).
// ---------------------------------------------------------------------------
template <bool F32, int P>
__device__ __forceinline__ void sumg(const void* Ur, int k, const float* hnc,
                                     float p0, float p1, const int* rowf,
                                     float& g0, float& g1) {
  float a[P];
#pragma unroll
  for (int p = 0; p < P; ++p) a[p] = rowf[p] ? p1 : p0;
  for (int i = 0; i < Hh; ++i) {
    float uv = ldv<F32>(Ur, (long)i * Hh + k);
#pragma unroll
    for (int p = 0; p < P; ++p) a[p] += hnc[p * Hh + i] * uv;
  }
#pragma unroll
  for (int p = 0; p < P; ++p) {
    float c = sigm(a[p]) * hnc[p * Hh + k];
    if (rowf[p]) g1 += c; else g0 += c;
  }
}

#define SUMG_SWITCH(F32V)                                                     \
  switch (P) {                                                                \
    case 1:  sumg<F32V, 1 >(Ur, k, hnc, p0, p1, rowf, g0, g1); break;         \
    case 2:  sumg<F32V, 2 >(Ur, k, hnc, p0, p1, rowf, g0, g1); break;         \
    case 3:  sumg<F32V, 3 >(Ur, k, hnc, p0, p1, rowf, g0, g1); break;         \
    case 4:  sumg<F32V, 4 >(Ur, k, hnc, p0, p1, rowf, g0, g1); break;         \
    case 5:  sumg<F32V, 5 >(Ur, k, hnc, p0, p1, rowf, g0, g1); break;         \
    case 6:  sumg<F32V, 6 >(Ur, k, hnc, p0, p1, rowf, g0, g1); break;         \
    case 7:  sumg<F32V, 7 >(Ur, k, hnc, p0, p1, rowf, g0, g1); break;         \
    case 8:  sumg<F32V, 8 >(Ur, k, hnc, p0, p1, rowf, g0, g1); break;         \
    case 9:  sumg<F32V, 9 >(Ur, k, hnc, p0, p1, rowf, g0, g1); break;         \
    case 10: sumg<F32V, 10>(Ur, k, hnc, p0, p1, rowf, g0, g1); break;         \
    case 11: sumg<F32V, 11>(Ur, k, hnc, p0, p1, rowf, g0, g1); break;         \
    case 12: sumg<F32V, 12>(Ur, k, hnc, p0, p1, rowf, g0, g1); break;         \
    case 13: sumg<F32V, 13>(Ur, k, hnc, p0, p1, rowf, g0, g1); break;         \
    case 14: sumg<F32V, 14>(Ur, k, hnc, p0, p1, rowf, g0, g1); break;         \
    case 15: sumg<F32V, 15>(Ur, k, hnc, p0, p1, rowf, g0, g1); break;         \
    case 16: sumg<F32V, 16>(Ur, k, hnc, p0, p1, rowf, g0, g1); break;         \
    default: break;                                                           \
  }

template <bool F32>
__device__ void gru_body(int t, const int* wid, const int* hni,
                         const void* emb, const void* Wz, const void* bz,
                         const void* Wr, const void* br, const void* Ur,
                         const void* Wh, const void* bh, bf16* hbuf,
                         float* xs, float* sh, float* sg, float* hnc,
                         int* cid, int* rowf, int* nvs) {
  const int k = threadIdx.x;
  const int b0 = blockIdx.x * 2;
  const int P = gru_prep(t, b0, hni, cid, rowf, nvs);

  const int w0 = wid[t * Bb + b0];
  const int w1 = wid[t * Bb + b0 + 1];
  xs[k]      = ldv<F32>(emb, (long)w0 * Hh + k);
  xs[Hh + k] = ldv<F32>(emb, (long)w1 * Hh + k);

  float s0 = 0.f, s1 = 0.f;
  for (int p = 0; p < P; ++p) {
    float hv = b2f(hbuf[(long)cid[p] * Hh + k]);
    hnc[p * Hh + k] = hv;
    if (rowf[p]) s1 += hv; else s0 += hv;
  }
  sh[k] = s0; sh[Hh + k] = s1;
  __syncthreads();

  float bzk = ldv<F32>(bz, k);
  float z0 = bzk, z1 = bzk;
  for (int i = 0; i < Hh; ++i) {
    float wv = ldv<F32>(Wz, (long)i * Hh + k);
    z0 += xs[i] * wv; z1 += xs[Hh + i] * wv;
  }
  for (int i = 0; i < Hh; ++i) {
    float wv = ldv<F32>(Wz, (long)(Hh + i) * Hh + k);
    z0 += sh[i] * wv; z1 += sh[Hh + i] * wv;
  }

  float brk = ldv<F32>(br, k);
  float p0 = brk, p1 = brk;
  for (int i = 0; i < Hh; ++i) {
    float wv = ldv<F32>(Wr, (long)i * Hh + k);
    p0 += xs[i] * wv; p1 += xs[Hh + i] * wv;
  }

  float g0 = 0.f, g1 = 0.f;
  SUMG_SWITCH(F32)
  sg[k] = g0; sg[Hh + k] = g1;
  __syncthreads();

  float bhk = ldv<F32>(bh, k);
  float h0 = bhk, h1 = bhk;
  for (int i = 0; i < Hh; ++i) {
    float wv = ldv<F32>(Wh, (long)i * Hh + k);
    h0 += xs[i] * wv; h1 += xs[Hh + i] * wv;
  }
  for (int i = 0; i < Hh; ++i) {
    float wv = ldv<F32>(Wh, (long)(Hh + i) * Hh + k);
    h0 += sg[i] * wv; h1 += sg[Hh + i] * wv;
  }

  float z;
  z = sigm(z0); float o0 = (1.f - z) * s0 + z * tanhf(h0);
  z = sigm(z1); float o1 = (1.f - z) * s1 + z * tanhf(h1);
  hbuf[((long)t * Bb + b0) * Hh + k]     = __float2bfloat16(o0);
  hbuf[((long)t * Bb + b0 + 1) * Hh + k] = __float2bfloat16(o1);
}

__global__ __launch_bounds__(512) void gru_step(
    int t, const int* __restrict__ wid, const int* __restrict__ hni,
    const void* emb, const void* Wz, const void* bz, const void* Wr,
    const void* br, const void* Ur, const void* Wh, const void* bh,
    bf16* hbuf, const int* __restrict__ flag) {
  __shared__ float xs[2 * Hh];
  __shared__ float sh[2 * Hh];
  __shared__ float sg[2 * Hh];
  __shared__ float hnc[2 * MAXNB * Hh];
  __shared__ int   cid[2 * MAXNB];
  __shared__ int   rowf[2 * MAXNB];
  __shared__ int   nvs[2];
  if (*flag)
    gru_body<true>(t, wid, hni, emb, Wz, bz, Wr, br, Ur, Wh, bh, hbuf,
                   xs, sh, sg, hnc, cid, rowf, nvs);
  else
    gru_body<false>(t, wid, hni, emb, Wz, bz, Wr, br, Ur, Wh, bh, hbuf,
                    xs, sh, sg, hnc, cid, rowf, nvs);
}

// ===========================================================================
// MFMA stop head, BM=16 / 256 threads / grid NROWS/16, tiled-B loads.
// (R11-proven, unchanged.)
// ===========================================================================
template <bool F32>
__device__ void stop_mfma_body(
    const void* mol_vec, const int* wid, const int* dirs, const int* oni,
    const int* root_wid, const int* roni, const void* emb,
    const bf16* __restrict__ wtU, const void* bU, const void* Us,
    const void* bs, const bf16* __restrict__ hbuf, float* accum,
    unsigned short* As, float* bU_l, float* Us_l, int* wl, int* bl,
    float* tgl, int* idsl, float* sred) {
  const int tid = threadIdx.x;
  const int l = tid & 63, w = tid >> 6;  // w: 0..3
  const int r0 = blockIdx.x * 16;

  bU_l[tid] = ldv<F32>(bU, tid);
  bU_l[tid + 256] = ldv<F32>(bU, tid + 256);
  Us_l[tid] = ldv<F32>(Us, tid);
  Us_l[tid + 256] = ldv<F32>(Us, tid + 256);
  if (tid < 16) {
    const int gi = r0 + tid;
    if (gi < TB) { wl[tid] = wid[gi]; bl[tid] = gi % Bb; tgl[tid] = (float)dirs[gi]; }
    else { const int j = gi - TB; wl[tid] = root_wid[j]; bl[tid] = j; tgl[tid] = 0.f; }
  }
  if (tid < 128) {
    const int rr = tid >> 3, jj = tid & 7;
    const int gi = r0 + rr;
    idsl[tid] = (gi < TB) ? oni[(long)gi * MAXNB + jj]
                          : roni[(long)(gi - TB) * MAXNB + jj];
  }
  __syncthreads();

  {
    const int rr = tid >> 4;   // 0..15
    const int c16 = tid & 15;
    const int wv_ = wl[rr], bv_ = bl[rr];
    for (int g = c16; g < 136; g += 16) {
      const int c8 = g * 8;
      int4 t;
      unsigned short* o = (unsigned short*)&t;
      if (c8 < 512) {
        if (F32) {
          const float* p = (const float*)emb + (long)wv_ * Hh + c8;
          const float4 a = *(const float4*)p, b = *(const float4*)(p + 4);
          o[0] = f2bfu(a.x); o[1] = f2bfu(a.y); o[2] = f2bfu(a.z); o[3] = f2bfu(a.w);
          o[4] = f2bfu(b.x); o[5] = f2bfu(b.y); o[6] = f2bfu(b.z); o[7] = f2bfu(b.w);
        } else {
          t = *(const int4*)((const bf16*)emb + (long)wv_ * Hh + c8);
        }
      } else if (c8 < 1024) {
        const int cc = c8 - 512;
        float s[8] = {0, 0, 0, 0, 0, 0, 0, 0};
        for (int j = 0; j < MAXNB; ++j) {
          const int id = idsl[rr * MAXNB + j];
          const int4 d = *(const int4*)(hbuf + (long)id * Hh + cc);
          const unsigned short* u = (const unsigned short*)&d;
#pragma unroll
          for (int e = 0; e < 8; ++e) s[e] += bfu(u[e]);
        }
#pragma unroll
        for (int e = 0; e < 8; ++e) o[e] = f2bfu(s[e]);
      } else {
        if (F32) {
          const float* p = (const float*)mol_vec + (long)bv_ * Ll + (c8 - 1024);
          const float4 a = *(const float4*)p, b = *(const float4*)(p + 4);
          o[0] = f2bfu(a.x); o[1] = f2bfu(a.y); o[2] = f2bfu(a.z); o[3] = f2bfu(a.w);
          o[4] = f2bfu(b.x); o[5] = f2bfu(b.y); o[6] = f2bfu(b.z); o[7] = f2bfu(b.w);
        } else {
          t = *(const int4*)((const bf16*)mol_vec + (long)bv_ * Ll + (c8 - 1024));
        }
      }
      *(int4*)&As[rr * KUP + c8] = t;
    }
  }
  __syncthreads();

  const int nq = w;
  const int arow = l & 15;
  const int kofs = (l >> 4) * 8;
  f32x4 acc[8];
#pragma unroll
  for (int f = 0; f < 8; ++f) acc[f] = (f32x4){0.f, 0.f, 0.f, 0.f};
  for (int k0 = 0; k0 < KU; k0 += 32) {
    const bf16x8 a = *(const bf16x8*)&As[arow * KUP + k0 + kofs];
    const bf16* bkb = wtU + ((long)(k0 >> 5) * NT_U + nq * 8) * 512 + l * 8;
#pragma unroll
    for (int f = 0; f < 8; ++f) {
      const bf16x8 b = *(const bf16x8*)(bkb + f * 512);
      acc[f] = __builtin_amdgcn_mfma_f32_16x16x32_bf16(a, b, acc[f], 0, 0, 0);
    }
  }

  float ps[4] = {0.f, 0.f, 0.f, 0.f};
#pragma unroll
  for (int f = 0; f < 8; ++f) {
    const int col = nq * 128 + f * 16 + (l & 15);
    const float bu = bU_l[col], us = Us_l[col];
#pragma unroll
    for (int r = 0; r < 4; ++r)
      ps[r] += fmaxf(acc[f][r] + bu, 0.f) * us;
  }
#pragma unroll
  for (int m = 1; m < 16; m <<= 1) {
#pragma unroll
    for (int r = 0; r < 4; ++r) ps[r] += __shfl_xor(ps[r], m, 64);
  }
  if ((l & 15) == 0) {
#pragma unroll
    for (int r = 0; r < 4; ++r)
      sred[((l >> 4) * 4 + r) * 4 + nq] = ps[r];
  }
  __syncthreads();

  if (tid < 16) {
    float s = sred[tid * 4] + sred[tid * 4 + 1] + sred[tid * 4 + 2] +
              sred[tid * 4 + 3] + ldv<F32>(bs, 0);
    const float tg = tgl[tid];
    float loss = fmaxf(s, 0.f) - s * tg + log1pf(expf(-fabsf(s)));
    float ok = ((s >= 0.5f) == (tg > 0.5f)) ? 1.f : 0.f;
#pragma unroll
    for (int m = 1; m < 16; m <<= 1) {
      loss += __shfl_xor(loss, m, 64);
      ok += __shfl_xor(ok, m, 64);
    }
    if (tid == 0) {
      atomicAdd(&accum[0], loss);
      atomicAdd(&accum[1], ok);
    }
  }
}

__global__ __launch_bounds__(256) void stop_mfma(
    const void* mol_vec, const int* __restrict__ wid,
    const int* __restrict__ dirs, const int* __restrict__ oni,
    const int* __restrict__ root_wid, const int* __restrict__ roni,
    const void* emb, const bf16* __restrict__ wtU, const void* bU,
    const void* Us, const void* bs, const bf16* __restrict__ hbuf,
    float* accum, const int* __restrict__ flag) {
  __shared__ __align__(16) unsigned short As[16 * KUP];  // 35 KB
  __shared__ float bU_l[Hh];
  __shared__ float Us_l[Hh];
  __shared__ int   wl[16];
  __shared__ int   bl[16];
  __shared__ float tgl[16];
  __shared__ int   idsl[16 * MAXNB];
  __shared__ float sred[16 * 4];
  if (*flag)
    stop_mfma_body<true>(mol_vec, wid, dirs, oni, root_wid, roni, emb, wtU,
                         bU, Us, bs, hbuf, accum, As, bU_l, Us_l, wl, bl, tgl,
                         idsl, sred);
  else
    stop_mfma_body<false>(mol_vec, wid, dirs, oni, root_wid, roni, emb, wtU,
                          bU, Us, bs, hbuf, accum, As, bU_l, Us_l, wl, bl,
                          tgl, idsl, sred);
}

// ===========================================================================
// MFMA pred head, BM=16 / 256 threads / grid NROWS/16, tiled-B loads.
// (R11-proven, unchanged.)
// ===========================================================================
template <bool F32>
__device__ void pred_mfma_body(
    const void* mol_vec, const int* y_wid, const int* dirs,
    const int* root_wid, const bf16* __restrict__ wtW, const void* bW,
    const bf16* __restrict__ wtWo, const void* bo,
    const bf16* __restrict__ hbuf, float* accum, unsigned short* As1,
    unsigned short* hidl, float* bW_l, float* bo_l, float* maxw, int* idxw,
    float* sumw, float* gmaxl, int* gidxl, float* sbl, int* tgtl,
    float* mskl) {
  const int tid = threadIdx.x;
  const int l = tid & 63, w = tid >> 6;  // w: 0..3
  const int r0 = blockIdx.x * 16;

  bW_l[tid] = ldv<F32>(bW, tid);
  bW_l[tid + 256] = ldv<F32>(bW, tid + 256);
  bo_l[tid] = ldv<F32>(bo, tid);
  bo_l[tid + 256] = ldv<F32>(bo, tid + 256);
  bo_l[tid + 512] = ldv<F32>(bo, tid + 512);
  bo_l[tid + 768] = ldv<F32>(bo, tid + 768);
  if (tid < 16) {
    const int gi = r0 + tid;
    if (gi < Bb) { tgtl[tid] = root_wid[gi]; mskl[tid] = 1.f; }
    else { tgtl[tid] = y_wid[gi - Bb]; mskl[tid] = (float)dirs[gi - Bb]; }
  }
  __syncthreads();

  {
    const int rr = tid >> 4;   // 0..15
    const int c16 = tid & 15;
    const int gi = r0 + rr;
    const int bv_ = (gi < Bb) ? gi : (gi - Bb) % Bb;
    for (int g = c16; g < 72; g += 16) {
      const int c8 = g * 8;
      int4 t;
      unsigned short* o = (unsigned short*)&t;
      if (c8 < 512) {
        if (gi < Bb) t = make_int4(0, 0, 0, 0);
        else t = *(const int4*)(hbuf + (long)(gi - Bb) * Hh + c8);
      } else {
        if (F32) {
          const float* p = (const float*)mol_vec + (long)bv_ * Ll + (c8 - 512);
          const float4 a = *(const float4*)p, b = *(const float4*)(p + 4);
          o[0] = f2bfu(a.x); o[1] = f2bfu(a.y); o[2] = f2bfu(a.z); o[3] = f2bfu(a.w);
          o[4] = f2bfu(b.x); o[5] = f2bfu(b.y); o[6] = f2bfu(b.z); o[7] = f2bfu(b.w);
        } else {
          t = *(const int4*)((const bf16*)mol_vec + (long)bv_ * Ll + (c8 - 512));
        }
      }
      *(int4*)&As1[rr * KWP + c8] = t;
    }
  }
  __syncthreads();

  const int nq = w;
  const int arow = l & 15;
  const int kofs = (l >> 4) * 8;

  // ---- L1: hid = relu(A1 @ W + bW), tiled-B ----
  {
    f32x4 acc1[8];
#pragma unroll
    for (int f = 0; f < 8; ++f) acc1[f] = (f32x4){0.f, 0.f, 0.f, 0.f};
    for (int k0 = 0; k0 < KW; k0 += 32) {
      const bf16x8 a = *(const bf16x8*)&As1[arow * KWP + k0 + kofs];
      const bf16* bkb = wtW + ((long)(k0 >> 5) * NT_U + nq * 8) * 512 + l * 8;
#pragma unroll
      for (int f = 0; f < 8; ++f) {
        const bf16x8 b = *(const bf16x8*)(bkb + f * 512);
        acc1[f] = __builtin_amdgcn_mfma_f32_16x16x32_bf16(a, b, acc1[f], 0, 0, 0);
      }
    }
#pragma unroll
    for (int f = 0; f < 8; ++f) {
      const int col = nq * 128 + f * 16 + (l & 15);
      const float bw = bW_l[col];
#pragma unroll
      for (int r = 0; r < 4; ++r) {
        const int row = (l >> 4) * 4 + r;
        hidl[row * HP + col] = f2bfu(fmaxf(acc1[f][r] + bw, 0.f));
      }
    }
  }
  __syncthreads();

  // ---- L2: logits = hid @ Wo + bo (kept in registers), tiled-B ----
  f32x4 acc2[16];
#pragma unroll
  for (int f = 0; f < 16; ++f) acc2[f] = (f32x4){0.f, 0.f, 0.f, 0.f};
  for (int k0 = 0; k0 < Hh; k0 += 32) {
    const bf16x8 a = *(const bf16x8*)&hidl[arow * HP + k0 + kofs];
    const bf16* bkb = wtWo + ((long)(k0 >> 5) * NT_WO + nq * 16) * 512 + l * 8;
#pragma unroll
    for (int f = 0; f < 16; ++f) {
      const bf16x8 b = *(const bf16x8*)(bkb + f * 512);
      acc2[f] = __builtin_amdgcn_mfma_f32_16x16x32_bf16(a, b, acc2[f], 0, 0, 0);
    }
  }

  // ---- CE: pass A (max/argmax) ----
  float vmax[4]; int vidx[4];
#pragma unroll
  for (int r = 0; r < 4; ++r) { vmax[r] = -3.4e38f; vidx[r] = 0; }
#pragma unroll
  for (int f = 0; f < 16; ++f) {
    const int col = nq * 256 + f * 16 + (l & 15);
    const float bv = bo_l[col];
#pragma unroll
    for (int r = 0; r < 4; ++r) {
      const float v = acc2[f][r] + bv;
      if (v > vmax[r]) { vmax[r] = v; vidx[r] = col; }
    }
  }
#pragma unroll
  for (int m = 1; m < 16; m <<= 1) {
#pragma unroll
    for (int r = 0; r < 4; ++r) {
      const float om = __shfl_xor(vmax[r], m, 64);
      const int oi = __shfl_xor(vidx[r], m, 64);
      if (om > vmax[r] || (om == vmax[r] && oi < vidx[r])) {
        vmax[r] = om; vidx[r] = oi;
      }
    }
  }
  if ((l & 15) == 0) {
#pragma unroll
    for (int r = 0; r < 4; ++r) {
      const int row = (l >> 4) * 4 + r;
      maxw[row * 4 + nq] = vmax[r];
      idxw[row * 4 + nq] = vidx[r];
    }
  }
  __syncthreads();
  if (tid < 16) {
    float gm = -3.4e38f; int gidx = 0;
    for (int q = 0; q < 4; ++q) {
      const float v = maxw[tid * 4 + q];
      const int i2 = idxw[tid * 4 + q];
      if (v > gm || (v == gm && i2 < gidx)) { gm = v; gidx = i2; }
    }
    gmaxl[tid] = gm; gidxl[tid] = gidx;
  }
  __syncthreads();

  // ---- CE: pass B (sum-exp + target logit) ----
  float se[4] = {0.f, 0.f, 0.f, 0.f};
#pragma unroll
  for (int f = 0; f < 16; ++f) {
    const int col = nq * 256 + f * 16 + (l & 15);
    const float bv = bo_l[col];
#pragma unroll
    for (int r = 0; r < 4; ++r) {
      const int row = (l >> 4) * 4 + r;
      const float v = acc2[f][r] + bv;
      se[r] += __expf(v - gmaxl[row]);
      if (col == tgtl[row]) sbl[row] = v;
    }
  }
#pragma unroll
  for (int m = 1; m < 16; m <<= 1) {
#pragma unroll
    for (int r = 0; r < 4; ++r) se[r] += __shfl_xor(se[r], m, 64);
  }
  if ((l & 15) == 0) {
#pragma unroll
    for (int r = 0; r < 4; ++r)
      sumw[((l >> 4) * 4 + r) * 4 + nq] = se[r];
  }
  __syncthreads();

  if (tid < 16) {
    const float ssum = sumw[tid * 4] + sumw[tid * 4 + 1] + sumw[tid * 4 + 2] +
                       sumw[tid * 4 + 3];
    const float lse = gmaxl[tid] + __logf(ssum);
    const float msk = mskl[tid];
    float pl = (lse - sbl[tid]) * msk;
    float pn = (gidxl[tid] == tgtl[tid]) ? msk : 0.f;
    float pm = msk;
#pragma unroll
    for (int m = 1; m < 16; m <<= 1) {
      pl += __shfl_xor(pl, m, 64);
      pn += __shfl_xor(pn, m, 64);
      pm += __shfl_xor(pm, m, 64);
    }
    if (tid == 0) {
      atomicAdd(&accum[2], pl);
      atomicAdd(&accum[3], pn);
      atomicAdd(&accum[4], pm);
    }
  }
}

__global__ __launch_bounds__(256) void pred_mfma(
    const void* mol_vec, const int* __restrict__ y_wid,
    const int* __restrict__ dirs, const int* __restrict__ root_wid,
    const bf16* __restrict__ wtW, const void* bW,
    const bf16* __restrict__ wtWo, const void* bo,
    const bf16* __restrict__ hbuf, float* accum,
    const int* __restrict__ flag) {
  __shared__ __align__(16) unsigned short As1[16 * KWP];   // 18.7 KB
  __shared__ __align__(16) unsigned short hidl[16 * HP];   // 16.6 KB
  __shared__ float bW_l[Hh];
  __shared__ float bo_l[Vv];
  __shared__ float maxw[16 * 4];
  __shared__ int   idxw[16 * 4];
  __shared__ float sumw[16 * 4];
  __shared__ float gmaxl[16];
  __shared__ int   gidxl[16];
  __shared__ float sbl[16];
  __shared__ int   tgtl[16];
  __shared__ float mskl[16];
  if (*flag)
    pred_mfma_body<true>(mol_vec, y_wid, dirs, root_wid, wtW, bW, wtWo, bo,
                         hbuf, accum, As1, hidl, bW_l, bo_l, maxw, idxw, sumw,
                         gmaxl, gidxl, sbl, tgtl, mskl);
  else
    pred_mfma_body<false>(mol_vec, y_wid, dirs, root_wid, wtW, bW, wtWo, bo,
                          hbuf, accum, As1, hidl, bW_l, bo_l, maxw, idxw,
                          sumw, gmaxl, gidxl, sbl, tgtl, mskl);
}

// ---------------------------------------------------------------------------
// VALU heads (fallback when workspace too small for MFMA buffers).
// ---------------------------------------------------------------------------
template <bool F32>
__device__ void stop_body(const void* mol_vec, const int* wid,
                          const int* dirs, const int* oni,
                          const int* root_wid, const int* roni,
                          const void* emb, const void* U, const void* bU,
                          const void* Us, const void* bs, const bf16* hbuf,
                          float* accum,
                          float (*srow)[2 * Hh + Ll], float (*red)[256],
                          float* fin) {
  const int tid = threadIdx.x;
  const int i0 = blockIdx.x * 8;
  const int K = 2 * Hh + Ll;  // 1088

  for (int r = 0; r < 8; ++r) {
    int i = i0 + r;
    int w, b;
    const int* ids;
    if (i < TB) { w = wid[i]; b = i % Bb; ids = &oni[(long)i * MAXNB]; }
    else { int j = i - TB; w = root_wid[j]; b = j; ids = &roni[(long)j * MAXNB]; }
    for (int c = tid; c < K; c += 256) {
      float v;
      if (c < Hh) v = ldv<F32>(emb, (long)w * Hh + c);
      else if (c < 2 * Hh) {
        int cc = c - Hh;
        float s = 0.f;
        for (int j = 0; j < MAXNB; ++j) s += b2f(hbuf[(long)ids[j] * Hh + cc]);
        v = s;
      } else v = ldv<F32>(mol_vec, (long)b * Ll + (c - 2 * Hh));
      srow[r][c] = v;
    }
  }
  __syncthreads();

  const int k0 = tid, k1 = tid + 256;
  float acc[8][2] = {};
  for (int kk = 0; kk < K; ++kk) {
    float u0 = ldv<F32>(U, (long)kk * Hh + k0);
    float u1 = ldv<F32>(U, (long)kk * Hh + k1);
#pragma unroll
    for (int r = 0; r < 8; ++r) {
      float a = srow[r][kk];
      acc[r][0] += a * u0; acc[r][1] += a * u1;
    }
  }
  float bU0 = ldv<F32>(bU, k0), bU1 = ldv<F32>(bU, k1);
  float us0 = ldv<F32>(Us, k0), us1 = ldv<F32>(Us, k1);
  __syncthreads();
#pragma unroll
  for (int r = 0; r < 8; ++r)
    red[r][tid] = fmaxf(acc[r][0] + bU0, 0.f) * us0 + fmaxf(acc[r][1] + bU1, 0.f) * us1;
  __syncthreads();
  for (int off = 128; off; off >>= 1) {
    if (tid < off) {
#pragma unroll
      for (int r = 0; r < 8; ++r) red[r][tid] += red[r][tid + off];
    }
    __syncthreads();
  }
  if (tid < 8) {
    int i = i0 + tid;
    float s = red[tid][0] + ldv<F32>(bs, 0);
    float tgt = (i < TB) ? (float)dirs[i] : 0.f;
    float loss = fmaxf(s, 0.f) - s * tgt + log1pf(expf(-fabsf(s)));
    float ok = ((s >= 0.5f) == (tgt > 0.5f)) ? 1.f : 0.f;
    fin[tid] = loss; fin[8 + tid] = ok;
  }
  __syncthreads();
  if (tid == 0) {
    float ls = 0.f, oks = 0.f;
    for (int r = 0; r < 8; ++r) { ls += fin[r]; oks += fin[8 + r]; }
    atomicAdd(&accum[0], ls);
    atomicAdd(&accum[1], oks);
  }
}

__global__ __launch_bounds__(256) void stop_kernel(
    const void* mol_vec, const int* __restrict__ wid,
    const int* __restrict__ dirs, const int* __restrict__ oni,
    const int* __restrict__ root_wid, const int* __restrict__ roni,
    const void* emb, const void* U, const void* bU, const void* Us,
    const void* bs, const bf16* hbuf, float* accum,
    const int* __restrict__ flag) {
  __shared__ float srow[8][2 * Hh + Ll];
  __shared__ float red[8][256];
  __shared__ float fin[16];
  if (*flag)
    stop_body<true>(mol_vec, wid, dirs, oni, root_wid, roni, emb, U, bU, Us,
                    bs, hbuf, accum, srow, red, fin);
  else
    stop_body<false>(mol_vec, wid, dirs, oni, root_wid, roni, emb, U, bU, Us,
                     bs, hbuf, accum, srow, red, fin);
}

template <bool F32>
__device__ void pred_body(const void* mol_vec, const int* y_wid,
                          const int* dirs, const int* root_wid, const void* W,
                          const void* bW, const void* Wo, const void* bo,
                          const bf16* hbuf, float* accum,
                          float (*srow)[Hh + Ll], float (*hid)[Hh],
                          float* rv, int* ri, float* sb) {
  const int tid = threadIdx.x;
  const int i0 = blockIdx.x * 8;
  const int K1 = Hh + Ll;  // 576

  for (int r = 0; r < 8; ++r) {
    int i = i0 + r;
    int b = (i < Bb) ? i : (i - Bb) % Bb;
    for (int c = tid; c < K1; c += 256) {
      float v;
      if (c < Hh) v = (i < Bb) ? 0.f : b2f(hbuf[(long)(i - Bb) * Hh + c]);
      else v = ldv<F32>(mol_vec, (long)b * Ll + (c - Hh));
      srow[r][c] = v;
    }
  }
  __syncthreads();

  const int k0 = tid, k1 = tid + 256;
  float acc[8][2] = {};
  for (int kk = 0; kk < K1; ++kk) {
    float w0 = ldv<F32>(W, (long)kk * Hh + k0);
    float w1 = ldv<F32>(W, (long)kk * Hh + k1);
#pragma unroll
    for (int r = 0; r < 8; ++r) {
      float a = srow[r][kk];
      acc[r][0] += a * w0; acc[r][1] += a * w1;
    }
  }
  float bW0 = ldv<F32>(bW, k0), bW1 = ldv<F32>(bW, k1);
#pragma unroll
  for (int r = 0; r < 8; ++r) {
    hid[r][k0] = fmaxf(acc[r][0] + bW0, 0.f);
    hid[r][k1] = fmaxf(acc[r][1] + bW1, 0.f);
  }
  __syncthreads();

  float lg[8][4] = {};
  for (int kk = 0; kk < Hh; ++kk) {
    float w0 = ldv<F32>(Wo, (long)kk * Vv + tid);
    float w1 = ldv<F32>(Wo, (long)kk * Vv + tid + 256);
    float w2 = ldv<F32>(Wo, (long)kk * Vv + tid + 512);
    float w3 = ldv<F32>(Wo, (long)kk * Vv + tid + 768);
#pragma unroll
    for (int r = 0; r < 8; ++r) {
      float a = hid[r][kk];
      lg[r][0] += a * w0; lg[r][1] += a * w1;
      lg[r][2] += a * w2; lg[r][3] += a * w3;
    }
  }
  float bo0 = ldv<F32>(bo, tid);
  float bo1 = ldv<F32>(bo, tid + 256);
  float bo2 = ldv<F32>(bo, tid + 512);
  float bo3 = ldv<F32>(bo, tid + 768);

  float plloss = 0.f, pnum = 0.f, pmask = 0.f;
  for (int r = 0; r < 8; ++r) {
    int i = i0 + r;
    int tgt = (i < Bb) ? root_wid[i] : y_wid[i - Bb];
    float msk = (i < Bb) ? 1.f : (float)dirs[i - Bb];
    float v0 = lg[r][0] + bo0, v1 = lg[r][1] + bo1;
    float v2 = lg[r][2] + bo2, v3 = lg[r][3] + bo3;

    float bm = v0; int bi = tid;
    if (v1 > bm) { bm = v1; bi = tid + 256; }
    if (v2 > bm) { bm = v2; bi = tid + 512; }
    if (v3 > bm) { bm = v3; bi = tid + 768; }
    rv[tid] = bm; ri[tid] = bi;
    if ((tgt & 255) == tid) {
      int cc = tgt >> 8;
      sb[0] = (cc == 0) ? v0 : (cc == 1) ? v1 : (cc == 2) ? v2 : v3;
    }
    __syncthreads();
    for (int off = 128; off; off >>= 1) {
      if (tid < off) {
        float o = rv[tid + off]; int oi = ri[tid + off];
        if (o > rv[tid] || (o == rv[tid] && oi < ri[tid])) { rv[tid] = o; ri[tid] = oi; }
      }
      __syncthreads();
    }
    float m = rv[0];
    int am = ri[0];
    __syncthreads();
    rv[tid] = __expf(v0 - m) + __expf(v1 - m) + __expf(v2 - m) + __expf(v3 - m);
    __syncthreads();
    for (int off = 128; off; off >>= 1) {
      if (tid < off) rv[tid] += rv[tid + off];
      __syncthreads();
    }
    if (tid == 0) {
      float lse = m + __logf(rv[0]);
      float ce = lse - sb[0];
      plloss += ce * msk;
      pnum += (am == tgt) ? msk : 0.f;
      pmask += msk;
    }
    __syncthreads();
  }
  if (tid == 0) {
    atomicAdd(&accum[2], plloss);
    atomicAdd(&accum[3], pnum);
    atomicAdd(&accum[4], pmask);
  }
}

__global__ __launch_bounds__(256) void pred_kernel(
    const void* mol_vec, const int* __restrict__ y_wid,
    const int* __restrict__ dirs, const int* __restrict__ root_wid,
    const void* W, const void* bW, const void* Wo, const void* bo,
    const bf16* hbuf, float* accum, const int* __restrict__ flag) {
  __shared__ float srow[8][Hh + Ll];
  __shared__ float hid[8][Hh];
  __shared__ float rv[256];
  __shared__ int   ri[256];
  __shared__ float sb[2];
  if (*flag)
    pred_body<true>(mol_vec, y_wid, dirs, root_wid, W, bW, Wo, bo, hbuf,
                    accum, srow, hid, rv, ri, sb);
  else
    pred_body<false>(mol_vec, y_wid, dirs, root_wid, W, bW, Wo, bo, hbuf,
                     accum, srow, hid, rv, ri, sb);
}

__global__ void finalize_kernel(const float* __restrict__ accum,
                                const int* __restrict__ flag, void* out) {
  if (threadIdx.x == 0 && blockIdx.x == 0) {
    float o0 = accum[2] / (float)Bb;      // pred_loss
    float o1 = accum[0] / (float)Bb;      // stop_loss
    float o2 = accum[3] / accum[4];       // pred_acc
    float o3 = accum[1] / (float)NROWS;   // stop_acc
    if (*flag) {
      float* o = (float*)out;
      o[0] = o0; o[1] = o1; o[2] = o2; o[3] = o3;
    } else {
      bf16* o = (bf16*)out;
      o[0] = __float2bfloat16(o0); o[1] = __float2bfloat16(o1);
      o[2] = __float2bfloat16(o2); o[3] = __float2bfloat16(o3);
    }
  }
}

extern "C" void kernel_launch(void* const* d_in, const int* in_sizes, int n_in,
                              void* d_out, int out_size, void* d_ws, size_t ws_size,
                              hipStream_t stream) {
  const void* mol_vec  = d_in[0];
  const int*  wid      = (const int*)d_in[1];
  const int*  y_wid    = (const int*)d_in[2];
  const int*  dirs     = (const int*)d_in[3];
  const int*  hni      = (const int*)d_in[4];
  const int*  oni      = (const int*)d_in[5];
  const int*  root_wid = (const int*)d_in[6];
  const int*  roni     = (const int*)d_in[7];
  const void* emb      = d_in[8];
  const void* Wz       = d_in[9];
  const void* bz       = d_in[10];
  const void* Wr       = d_in[11];
  const void* br       = d_in[12];
  const void* Ur       = d_in[13];
  const void* Wh       = d_in[14];
  const void* bh       = d_in[15];
  const void* W        = d_in[16];
  const void* bW       = d_in[17];
  const void* U        = d_in[18];
  const void* bU       = d_in[19];
  const void* Wo       = d_in[20];
  const void* bo       = d_in[21];
  const void* Us       = d_in[22];
  const void* bs       = d_in[23];

  // ws: [accum 8f][flag 1i][pad->64B][hbuf][xproj][wtW][wtU][wtWo][wgZ][wgR][wgH2]
  float* accum = (float*)d_ws;
  int*   flag  = (int*)d_ws + 8;
  bf16*  hbuf  = (bf16*)((char*)d_ws + 64);
  bf16*  xproj = hbuf + (long)(TB + 1) * Hh;
  bf16*  wtW   = xproj + (long)Vv * XPS;
  bf16*  wtU   = wtW + (long)Hh * KW;
  bf16*  wtWo  = wtU + (long)Hh * KU;
  bf16*  wgZ   = wtWo + (long)Vv * Hh;
  bf16*  wgR   = wgZ + (long)Hh * Hh;
  bf16*  wgH2  = wgR + (long)Hh * Hh;

  const size_t need_xp = 64 + ((size_t)(TB + 1) * Hh + (size_t)Vv * XPS) * sizeof(bf16);
  const size_t need_m  = need_xp +
      ((size_t)Hh * KW + (size_t)Hh * KU + (size_t)Vv * Hh) * sizeof(bf16);
  const size_t need_g  = need_m + 3ull * Hh * Hh * sizeof(bf16);
  const bool use_xp = (ws_size >= need_xp);  // constant across calls: graph-safe
  const bool useM   = (ws_size >= need_m);
  const bool useG   = (ws_size >= need_g);

  hipMemsetAsync(d_ws, 0, 64, stream);                                   // accum+flag
  hipMemsetAsync(hbuf + (long)TB * Hh, 0, Hh * sizeof(bf16), stream);    // PAD row

  detect_kernel<<<64, 256, 0, stream>>>((const unsigned short*)emb, flag);

  if (useM) {
    const int nblk = useG ? 528 : 336;  // +192 tiles for wgZ/wgR/wgH2
    wt_kernel<<<nblk, 256, 0, stream>>>(W, U, Wo, Wz, Ur, Wh, wtW, wtU, wtWo,
                                        wgZ, wgR, wgH2, flag);
  }
  if (use_xp) {
    xproj_kernel<<<Vv, 512, 0, stream>>>(emb, Wz, bz, Wr, br, Wh, bh, xproj, flag);
    if (useG) {
      for (int t = 0; t < Tt; ++t) {
        gru_step_xpb<<<Bb / 2, 512, 0, stream>>>(t, wid, hni, xproj, wgZ, wgR,
                                                 wgH2, hbuf);
      }
    } else {
      for (int t = 0; t < Tt; ++t) {
        gru_step_xp<<<Bb / 2, 512, 0, stream>>>(t, wid, hni, xproj, Wz, Ur,
                                                Wh, hbuf, flag);
      }
    }
  } else {
    for (int t = 0; t < Tt; ++t) {
      gru_step<<<Bb / 2, 512, 0, stream>>>(t, wid, hni, emb, Wz, bz, Wr, br,
                                           Ur, Wh, bh, hbuf, flag);
    }
  }

  if (useM) {
    stop_mfma<<<NROWS / 16, 256, 0, stream>>>(mol_vec, wid, dirs, oni,
                                              root_wid, roni, emb, wtU, bU, Us,
                                              bs, hbuf, accum, flag);
    pred_mfma<<<NROWS / 16, 256, 0, stream>>>(mol_vec, y_wid, dirs, root_wid,
                                              wtW, bW, wtWo, bo, hbuf, accum,
                                              flag);
  } else {
    stop_kernel<<<NROWS / 8, 256, 0, stream>>>(mol_vec, wid, dirs, oni,
                                               root_wid, roni, emb, U, bU, Us,
                                               bs, hbuf, accum, flag);
    pred_kernel<<<NROWS / 8, 256, 0, stream>>>(mol_vec, y_wid, dirs, root_wid,
                                               W, bW, Wo, bo, hbuf, accum,
                                               flag);
  }
  finalize_kernel<<<1, 64, 0, stream>>>(accum, flag, d_out);
}